// Round 5
// baseline (386.575 us; speedup 1.0000x reference)
//
#include <hip/hip_runtime.h>
#include <hip/hip_bf16.h>
#include <math.h>

// Problem constants
constexpr int Bc  = 2;
constexpr int Tc  = 2048;
constexpr int Dc  = 768;
constexpr int Hc  = 12;
constexpr int DHc = 64;
constexpr int M_ROWS = Bc * Tc;        // 4096
constexpr int D3  = 3 * Dc;            // 2304
constexpr int D4  = 4 * Dc;            // 3072

typedef __attribute__((ext_vector_type(8))) short short8;   // 8 bf16 (4 VGPRs)
typedef __attribute__((ext_vector_type(4))) float f32x4;    // MFMA acc

__device__ __forceinline__ unsigned short f2bf(float v) {
    union { __hip_bfloat16 b; unsigned short u; } cv;
    cv.b = __float2bfloat16(v);
    return cv.u;
}
__device__ __forceinline__ float bf2f(unsigned short u) {
    union { __hip_bfloat16 b; unsigned short u; } cv;
    cv.u = u;
    return __bfloat162float(cv.b);
}
__device__ __forceinline__ void bsplit(float v, unsigned short& h, unsigned short& l) {
    h = f2bf(v);
    l = f2bf(v - bf2f(h));
}

__device__ __forceinline__ float gelu_f(float x) {
    const float c = 0.79788456080286535588f; // sqrt(2/pi)
    return 0.5f * x * (1.0f + tanhf(c * (x + 0.044715f * x * x * x)));
}

// Async global->LDS, 16B per lane (LDS dest = wave-uniform base + lane*16).
__device__ __forceinline__ void glds16(const unsigned short* g, unsigned short* l) {
    __builtin_amdgcn_global_load_lds(
        (const __attribute__((address_space(1))) void*)g,
        (__attribute__((address_space(3))) void*)l, 16, 0, 0);
}

// ---------------------------------------------------------------------------
// Fused prepare: x cast + all 4 weight transpose-casts in ONE dispatch.
// ---------------------------------------------------------------------------
__device__ __forceinline__ void tcast8(
    const float* __restrict__ w, int ldw,
    unsigned short* __restrict__ th, int K, int N, int idx)
{
    const int n  = idx % N;
    const int k0 = (idx / N) * 8;
    unsigned short hv[8];
#pragma unroll
    for (int j = 0; j < 8; ++j)
        hv[j] = f2bf(w[(size_t)(k0 + j) * ldw + n]);
    const size_t o = (size_t)n * K + k0;
    *(ushort4*)(th + o)     = make_ushort4(hv[0], hv[1], hv[2], hv[3]);
    *(ushort4*)(th + o + 4) = make_ushort4(hv[4], hv[5], hv[6], hv[7]);
}

__global__ __launch_bounds__(256) void prepare_kernel(
    const float* __restrict__ x,
    const float* __restrict__ w_qkv, const float* __restrict__ w_proj,
    const float* __restrict__ w_fc,  const float* __restrict__ w_out,
    unsigned short* __restrict__ xh,
    unsigned short* __restrict__ wqkvT, unsigned short* __restrict__ wprojT,
    unsigned short* __restrict__ wfcT,  unsigned short* __restrict__ woutT)
{
    int id = blockIdx.x * 256 + threadIdx.x;
    if (id < 786432) {
        const float4 v = *(const float4*)(x + (size_t)id * 4);
        *(ushort4*)(xh + (size_t)id * 4) =
            make_ushort4(f2bf(v.x), f2bf(v.y), f2bf(v.z), f2bf(v.w));
        return;
    }
    id -= 786432;
    if (id < 221184) { tcast8(w_qkv, D3, wqkvT, Dc, D3, id); return; }
    id -= 221184;
    if (id < 73728)  { tcast8(w_proj, Dc, wprojT, Dc, Dc, id); return; }
    id -= 73728;
    if (id < 294912) { tcast8(w_fc, D4, wfcT, Dc, D4, id); return; }
    id -= 294912;
    tcast8(w_out, Dc, woutT, D4, Dc, id);
}

// ---------------------------------------------------------------------------
// gemm256p8: 256x256-tile bf16 MFMA GEMM, 8 waves (512 thr), 8-PHASE
// schedule (m201 port). dbuf BK=64. Per K-tile: 4 phases, each computing one
// 64x32 output quadrant:
//   { 12x ds_read_b128 (quadrant frags from buf[cur])
//     ∥ 4x glds16 (tile t+1 -> buf[nxt], phases 0-1 only)
//     s_barrier  (raw: glds16s stay in flight)
//     setprio(1); 16x MFMA; setprio(0)
//     s_barrier }
// Tile boundary: s_waitcnt vmcnt(0) (loads had >=2.5 phases to land; with a
// 2-buffer LDS this wait is semantically exact, not a forced drain) + barrier.
// Geometry identical to the verified 2-phase kernel: M fixed 4096 (16 row-
// tiles), N%256==0, K%64==0, grid%8==0, bijective XCD swizzle, per-wave
// output 128x64 (acc[8][4]). LDS rows 64 shorts contiguous (glds16 req);
// 16B chunks XOR-swizzled on the GLOBAL side (phys chunk p of row r =
// p^(r&7)); frag reads un-swizzle with one XOR -> 2 lanes/bank (free, m136).
// MODE: 0 = fp32 out (+bias) | 1 = gelu -> bf16 out (+bias) | 3 = bf16 out
// ---------------------------------------------------------------------------
template <int MODE>
__global__ __launch_bounds__(512) void gemm256p8(
    const unsigned short* __restrict__ A,
    const unsigned short* __restrict__ B,
    const float* __restrict__ bias,
    float* __restrict__ C, unsigned short* __restrict__ Cb,
    int N, int K)
{
    __shared__ unsigned short Ash[2][256 * 64];   // 64 KB
    __shared__ unsigned short Bsh[2][256 * 64];   // 64 KB

    const int tid  = threadIdx.x;
    const int wave = tid >> 6;
    const int lane = tid & 63;

    // bijective XCD swizzle (gridDim.x % 8 == 0), column-major grouping
    const int nper = gridDim.x >> 3;
    const int gid  = (blockIdx.x & 7) * nper + (blockIdx.x >> 3);
    const int bx   = gid / 16;               // N-tile
    const int by   = gid % 16;               // M-tile (M/256 = 16)
    const int m0 = by * 256, n0 = bx * 256;

    const int wm   = (wave >> 2) * 128;      // 2 M-halves
    const int wn   = (wave & 3) * 64;        // 4 N-quarters
    const int lrow = lane & 15;
    const int quad = lane >> 4;
    const int swz  = lrow & 7;

    f32x4 acc[8][4];
    const f32x4 zero = {0.f, 0.f, 0.f, 0.f};
#pragma unroll
    for (int i = 0; i < 8; ++i)
#pragma unroll
        for (int j = 0; j < 4; ++j) acc[i][j] = zero;

    const int l8r  = lane >> 3;              // row within an 8-row issue
    const int csel = ((lane & 7) ^ l8r) * 8; // swizzled global chunk (shorts)

    const int nsteps = K >> 6;

    // prologue: stage tile 0 into buf 0 (8 glds16/wave), exact wait, barrier
#pragma unroll
    for (int j = 0; j < 4; ++j) {
        const int rb = wave * 32 + j * 8;
        glds16(A + (size_t)(m0 + rb + l8r) * K + csel, &Ash[0][rb * 64]);
        glds16(B + (size_t)(n0 + rb + l8r) * K + csel, &Bsh[0][rb * 64]);
    }
    asm volatile("s_waitcnt vmcnt(0)" ::: "memory");
    __builtin_amdgcn_s_barrier();
    __builtin_amdgcn_sched_barrier(0);

    for (int s = 0; s < nsteps; ++s) {
        const int cur = s & 1;
        const int nxt = cur ^ 1;
        const bool pf = (s + 1 < nsteps);
        const int ksn = (s + 1) << 6;

#pragma unroll
        for (int p = 0; p < 4; ++p) {
            const int mh = (p >> 1) * 4;     // mt base of this quadrant
            const int nh = (p & 1) * 2;      // nt base

            // ---- 12x ds_read_b128: quadrant fragments ----
            short8 fa[4][2], fb[2][2];
#pragma unroll
            for (int kk = 0; kk < 2; ++kk) {
                const int pc = ((kk * 4 + quad) ^ swz) * 8;
#pragma unroll
                for (int i = 0; i < 4; ++i)
                    fa[i][kk] = *(const short8*)
                        &Ash[cur][(wm + (mh + i) * 16 + lrow) * 64 + pc];
#pragma unroll
                for (int j = 0; j < 2; ++j)
                    fb[j][kk] = *(const short8*)
                        &Bsh[cur][(wn + (nh + j) * 16 + lrow) * 64 + pc];
            }

            // ---- stage issues for tile s+1 (front-loaded: phases 0,1) ----
            if (pf && p < 2) {
#pragma unroll
                for (int j = 0; j < 2; ++j) {
                    const int rb = wave * 32 + (p * 2 + j) * 8;
                    glds16(A + (size_t)(m0 + rb + l8r) * K + ksn + csel,
                           &Ash[nxt][rb * 64]);
                    glds16(B + (size_t)(n0 + rb + l8r) * K + ksn + csel,
                           &Bsh[nxt][rb * 64]);
                }
            }

            __builtin_amdgcn_s_barrier();    // raw: loads stay in flight

            __builtin_amdgcn_s_setprio(1);
#pragma unroll
            for (int kk = 0; kk < 2; ++kk)
#pragma unroll
                for (int i = 0; i < 4; ++i)
#pragma unroll
                    for (int j = 0; j < 2; ++j)
                        acc[mh + i][nh + j] = __builtin_amdgcn_mfma_f32_16x16x32_bf16(
                            fa[i][kk], fb[j][kk], acc[mh + i][nh + j], 0, 0, 0);
            __builtin_amdgcn_s_setprio(0);

            if (p < 3) __builtin_amdgcn_s_barrier();
        }

        // tile boundary: all of tile s+1 landed; all reads of buf[cur] done
        asm volatile("s_waitcnt vmcnt(0)" ::: "memory");
        __builtin_amdgcn_s_barrier();
        __builtin_amdgcn_sched_barrier(0);
    }

#pragma unroll
    for (int mt = 0; mt < 8; ++mt) {
        const int rowb = m0 + wm + mt * 16 + quad * 4;
#pragma unroll
        for (int nt = 0; nt < 4; ++nt) {
            const int col = n0 + wn + nt * 16 + lrow;
            const float bv = bias[col];
#pragma unroll
            for (int r = 0; r < 4; ++r) {
                const size_t ci = (size_t)(rowb + r) * N + col;
                if (MODE == 0) {
                    C[ci] = acc[mt][nt][r] + bv;
                } else if (MODE == 1) {
                    Cb[ci] = f2bf(gelu_f(acc[mt][nt][r] + bv));
                } else { // MODE 3
                    Cb[ci] = f2bf(acc[mt][nt][r] + bv);
                }
            }
        }
    }
}

// ---------------------------------------------------------------------------
// bf16 MFMA flash attention, v5:
//  - K/V LDS double-buffered -> ONE barrier per K-tile (was two). Safety:
//    stores into buf[c] only conflict with reads from iteration kt-2, which
//    finished before the kt-1 barrier. PfU is wave-private (no barrier).
//  - register prefetch issued AFTER the barrier (flies under compute; the
//    barrier's implicit vmcnt drain only sees already-landed loads)
//  - setprio(1) around QK and PV MFMA clusters (T5, attn-proven +4-7%)
//  - everything else (masking, exp2, Vt swizzle) unchanged from v4
// LDS: 2*Kh + 2*Vt + PfU = 5 * 64*72*2 B = 46 KB (grid-limited residency
// unchanged at 3 blocks/CU).
// ---------------------------------------------------------------------------
constexpr int KS  = 72;  // K/V LDS row stride (shorts): 144B rows, 16B-aligned
constexpr int PS2 = 72;  // P LDS row stride (shorts)

__global__ __launch_bounds__(256) void flash_attn_bf16(
    const unsigned short* __restrict__ qkv,
    const int* __restrict__ lengths,
    unsigned short* __restrict__ oh)
{
    __shared__ unsigned short Kh[2][64 * KS];
    __shared__ unsigned short Vt[2][64 * KS];  // V^T: [d][k], chunk-swizzled
    __shared__ unsigned short PfU[64 * PS2];   // P bf16, wave-private strips

    const int tid  = threadIdx.x;
    const int wave = tid >> 6;
    const int lane = tid & 63;
    const int m    = lane & 15;
    const int quad = lane >> 4;

    const int nqt = Tc / 64;                  // 32
    const int qt  = blockIdx.x % nqt;
    const int bh  = blockIdx.x / nqt;
    const int hh  = bh % Hc;
    const int b   = bh / Hc;
    const int len = lengths[b];
    const int q0  = qt * 64;
    const size_t rs = (size_t)D3;
    const unsigned short* base = qkv + (size_t)b * Tc * rs;
    const int qcol = hh * DHc;
    const int kcol = Dc + hh * DHc;
    const int vcol = 2 * Dc + hh * DHc;

    // ---- q-tile fully masked: write zeros, done ----
    if (q0 >= len) {
#pragma unroll
        for (int r = 0; r < 4; ++r) {
            const int qrow = q0 + wave * 16 + quad * 4 + r;
            const size_t ob = (size_t)(b * Tc + qrow) * Dc + hh * DHc + m;
#pragma unroll
            for (int nt = 0; nt < 4; ++nt) oh[ob + nt * 16] = 0;
        }
        return;
    }

    const int ktEnd = (min(len, Tc) + 63) >> 6;   // skip fully-masked K tiles

    // ---- preload Q fragments (A-layout), pre-scaled by log2(e) ----
    short8 Qf[2];
#pragma unroll
    for (int ch = 0; ch < 2; ++ch) {
        const size_t ga = (size_t)(q0 + wave * 16 + m) * rs + qcol + ch * 32 + quad * 8;
        const short8 q8 = *(const short8*)&base[ga];
        short8 qs;
#pragma unroll
        for (int j = 0; j < 8; ++j)
            qs[j] = (short)f2bf(bf2f((unsigned short)q8[j]) * 1.44269504088896f);
        Qf[ch] = qs;
    }

    f32x4 Oacc[4];
    const f32x4 zero = {0.f, 0.f, 0.f, 0.f};
#pragma unroll
    for (int nt = 0; nt < 4; ++nt) Oacc[nt] = zero;
    float lrow[4] = {0.f, 0.f, 0.f, 0.f};     // per-lane partial row sums

    // staging maps
    const int kr0 = tid >> 3,          kc0 = (tid & 7) * 8;          // rows 0..31
    const int kr1 = (tid + 256) >> 3,  kc1 = ((tid + 256) & 7) * 8;  // rows 32..63
    const int pk  = (tid >> 4) * 4;      // V patch: k-base (0,4,8,12)
    const int pd  = (tid & 15) * 4;      // V patch: d-base (0..60)
    // Vt swizzle: phys chunk = (k>>3) ^ ((d>>2)&7); uniform per thread-patch.
    const int vswz = ((pk >> 3) ^ ((pd >> 2) & 7)) * 8 + (pk & 7);

    // prefetch registers
    short8  pK0, pK1;
    ushort4 pV0, pV1, pV2, pV3;
    {   // load tile 0
        pK0 = *(const short8*)&base[(size_t)kr0 * rs + kcol + kc0];
        pK1 = *(const short8*)&base[(size_t)kr1 * rs + kcol + kc1];
        pV0 = *(const ushort4*)&base[(size_t)(pk + 0) * rs + vcol + pd];
        pV1 = *(const ushort4*)&base[(size_t)(pk + 1) * rs + vcol + pd];
        pV2 = *(const ushort4*)&base[(size_t)(pk + 2) * rs + vcol + pd];
        pV3 = *(const ushort4*)&base[(size_t)(pk + 3) * rs + vcol + pd];
    }

    for (int kt = 0; kt < ktEnd; ++kt) {
        const int kbase = kt * 64;
        const int c = kt & 1;

        // ---- stage prefetched K/V to LDS buf[c] (Vt chunk-swizzled) ----
        *(short8*)&Kh[c][kr0 * KS + kc0] = pK0;
        *(short8*)&Kh[c][kr1 * KS + kc1] = pK1;
        *(ushort4*)&Vt[c][(pd + 0) * KS + vswz] = make_ushort4(pV0.x, pV1.x, pV2.x, pV3.x);
        *(ushort4*)&Vt[c][(pd + 1) * KS + vswz] = make_ushort4(pV0.y, pV1.y, pV2.y, pV3.y);
        *(ushort4*)&Vt[c][(pd + 2) * KS + vswz] = make_ushort4(pV0.z, pV1.z, pV2.z, pV3.z);
        *(ushort4*)&Vt[c][(pd + 3) * KS + vswz] = make_ushort4(pV0.w, pV1.w, pV2.w, pV3.w);
        __syncthreads();   // single barrier per K-tile

        // ---- issue loads for tile kt+1 (fly under compute below) ----
        if (kt + 1 < ktEnd) {
            const int nb = kbase + 64;
            pK0 = *(const short8*)&base[(size_t)(nb + kr0) * rs + kcol + kc0];
            pK1 = *(const short8*)&base[(size_t)(nb + kr1) * rs + kcol + kc1];
            pV0 = *(const ushort4*)&base[(size_t)(nb + pk + 0) * rs + vcol + pd];
            pV1 = *(const ushort4*)&base[(size_t)(nb + pk + 1) * rs + vcol + pd];
            pV2 = *(const ushort4*)&base[(size_t)(nb + pk + 2) * rs + vcol + pd];
            pV3 = *(const ushort4*)&base[(size_t)(nb + pk + 3) * rs + vcol + pd];
        }

        // ---- S' = (Q*log2e) · K^T ----
        f32x4 S4[4];
#pragma unroll
        for (int nt = 0; nt < 4; ++nt) S4[nt] = zero;
        __builtin_amdgcn_s_setprio(1);
#pragma unroll
        for (int ch = 0; ch < 2; ++ch)
#pragma unroll
            for (int nt = 0; nt < 4; ++nt) {
                const short8 k8 = *(const short8*)&Kh[c][(nt * 16 + m) * KS + ch * 32 + quad * 8];
                S4[nt] = __builtin_amdgcn_mfma_f32_16x16x32_bf16(Qf[ch], k8, S4[nt], 0, 0, 0);
            }
        __builtin_amdgcn_s_setprio(0);

        // ---- mask invalid keys (exp2(-1e30) underflows to exact 0) ----
        if (kbase + 64 > len) {
#pragma unroll
            for (int nt = 0; nt < 4; ++nt)
                if (kbase + nt * 16 + m >= len) {
#pragma unroll
                    for (int r = 0; r < 4; ++r) S4[nt][r] = -1e30f;
                }
        }

        // ---- p = exp2(S'); accumulate partial l; store P (bf16) ----
#pragma unroll
        for (int nt = 0; nt < 4; ++nt)
#pragma unroll
            for (int r = 0; r < 4; ++r) {
                const float p = __builtin_amdgcn_exp2f(S4[nt][r]);
                lrow[r] += p;
                PfU[(wave * 16 + quad * 4 + r) * PS2 + nt * 16 + m] = f2bf(p);
            }

        // ---- O += P · V (Vt read un-swizzled per (nt,ch,quad,m)) ----
#pragma unroll
        for (int ch = 0; ch < 2; ++ch) {
            const short8 P8 = *(const short8*)&PfU[(wave * 16 + m) * PS2 + ch * 32 + quad * 8];
            __builtin_amdgcn_s_setprio(1);
#pragma unroll
            for (int nt = 0; nt < 4; ++nt) {
                const int pchunk = ((ch * 4 + quad) ^ ((nt * 4 + (m >> 2)) & 7)) * 8;
                const short8 v8 = *(const short8*)&Vt[c][(nt * 16 + m) * KS + pchunk];
                Oacc[nt] = __builtin_amdgcn_mfma_f32_16x16x32_bf16(P8, v8, Oacc[nt], 0, 0, 0);
            }
            __builtin_amdgcn_s_setprio(0);
        }
    }

    // ---- single end-of-loop row-sum reduction over the 16 m-lanes ----
#pragma unroll
    for (int r = 0; r < 4; ++r) {
#pragma unroll
        for (int sh = 8; sh >= 1; sh >>= 1)
            lrow[r] += __shfl_xor(lrow[r], sh);
    }

    // ---- epilogue: /l, zero invalid q rows, bf16 store ----
#pragma unroll
    for (int r = 0; r < 4; ++r) {
        const int qrow = q0 + wave * 16 + quad * 4 + r;
        const size_t ob = (size_t)(b * Tc + qrow) * Dc + hh * DHc + m;
        if (qrow < len) {
            const float inv = 1.0f / lrow[r];
#pragma unroll
            for (int nt = 0; nt < 4; ++nt)
                oh[ob + nt * 16] = f2bf(Oacc[nt][r] * inv);
        } else {
#pragma unroll
            for (int nt = 0; nt < 4; ++nt)
                oh[ob + nt * 16] = 0;
        }
    }
}

// ---------------------------------------------------------------------------
// LN1: (outh,outl) = split_bf16(LN(X + Y) * mask). X,Y fp32.
// ---------------------------------------------------------------------------
__global__ __launch_bounds__(256) void ln_split_kernel(
    const float* __restrict__ X, const float* __restrict__ Y,
    const float* __restrict__ g, const float* __restrict__ beta,
    const int* __restrict__ lengths,
    unsigned short* __restrict__ outh, unsigned short* __restrict__ outl)
{
    __shared__ float red[4];
    const int row = blockIdx.x;
    const int b = row / Tc, t = row % Tc;
    const int len = lengths[b];
    const size_t basei = (size_t)row * Dc;
    const int tid = threadIdx.x;

    if (t >= len) {
        for (int j = tid; j < Dc; j += 256) { outh[basei + j] = 0; outl[basei + j] = 0; }
        return;
    }

    float v[3];
    float s = 0.f;
#pragma unroll
    for (int j = 0; j < 3; ++j) {
        int idx = tid + j * 256;
        v[j] = X[basei + idx] + Y[basei + idx];
        s += v[j];
    }
    const int lane = tid % 64, wid = tid / 64;
#pragma unroll
    for (int sh = 32; sh >= 1; sh >>= 1) s += __shfl_xor(s, sh);
    if (lane == 0) red[wid] = s;
    __syncthreads();
    s = red[0] + red[1] + red[2] + red[3];
    const float mu = s * (1.0f / Dc);

    float vs = 0.f;
#pragma unroll
    for (int j = 0; j < 3; ++j) { float dv = v[j] - mu; vs += dv * dv; }
    __syncthreads();
#pragma unroll
    for (int sh = 32; sh >= 1; sh >>= 1) vs += __shfl_xor(vs, sh);
    if (lane == 0) red[wid] = vs;
    __syncthreads();
    vs = red[0] + red[1] + red[2] + red[3];
    const float rstd = rsqrtf(vs * (1.0f / Dc) + 1e-5f);

#pragma unroll
    for (int j = 0; j < 3; ++j) {
        int idx = tid + j * 256;
        const float ov = (v[j] - mu) * rstd * g[idx] + beta[idx];
        unsigned short hh, ll;
        bsplit(ov, hh, ll);
        outh[basei + idx] = hh;
        outl[basei + idx] = ll;
    }
}

// ---------------------------------------------------------------------------
// LN2: out = LN((Xh+Xl) + Y) * mask, fp32 out. Y and out may alias (in-place).
// ---------------------------------------------------------------------------
__global__ __launch_bounds__(256) void ln2_kernel(
    const unsigned short* __restrict__ Xh, const unsigned short* __restrict__ Xl,
    const float* Y,
    const float* __restrict__ g, const float* __restrict__ beta,
    const int* __restrict__ lengths, float* out)
{
    __shared__ float red[4];
    const int row = blockIdx.x;
    const int b = row / Tc, t = row % Tc;
    const int len = lengths[b];
    const size_t basei = (size_t)row * Dc;
    const int tid = threadIdx.x;

    if (t >= len) {
        for (int j = tid; j < Dc; j += 256) out[basei + j] = 0.f;
        return;
    }

    float v[3];
    float s = 0.f;
#pragma unroll
    for (int j = 0; j < 3; ++j) {
        int idx = tid + j * 256;
        v[j] = bf2f(Xh[basei + idx]) + bf2f(Xl[basei + idx]) + Y[basei + idx];
        s += v[j];
    }
    const int lane = tid % 64, wid = tid / 64;
#pragma unroll
    for (int sh = 32; sh >= 1; sh >>= 1) s += __shfl_xor(s, sh);
    if (lane == 0) red[wid] = s;
    __syncthreads();
    s = red[0] + red[1] + red[2] + red[3];
    const float mu = s * (1.0f / Dc);

    float vs = 0.f;
#pragma unroll
    for (int j = 0; j < 3; ++j) { float dv = v[j] - mu; vs += dv * dv; }
    __syncthreads();
#pragma unroll
    for (int sh = 32; sh >= 1; sh >>= 1) vs += __shfl_xor(vs, sh);
    if (lane == 0) red[wid] = vs;
    __syncthreads();
    vs = red[0] + red[1] + red[2] + red[3];
    const float rstd = rsqrtf(vs * (1.0f / Dc) + 1e-5f);

#pragma unroll
    for (int j = 0; j < 3; ++j) {
        int idx = tid + j * 256;
        out[basei + idx] = (v[j] - mu) * rstd * g[idx] + beta[idx];
    }
}

// ---------------------------------------------------------------------------
// Workspace plan (bytes; peak 51,904,512 — unchanged):
//   [0, 18.87M)        : qkvh -> projo fp32 [0,12.58M) -> fH head
//   [18.87M, 25.17M)   : xh -> ah -> fH tail  (fH = [0,25.17M) [4096,3072])
//   [25.17M, 31.46M)   : nh | [31.46M, 37.75M) : nl
//   [37.75M, 41.29M)   : wqkvT | [41.29M, 42.47M) : wprojT
//   [42.47M, 47.19M)   : wfcT  | [47.19M, 51.91M) : woutT
// ---------------------------------------------------------------------------
extern "C" void kernel_launch(void* const* d_in, const int* in_sizes, int n_in,
                              void* d_out, int out_size, void* d_ws, size_t ws_size,
                              hipStream_t stream)
{
    const float* x      = (const float*)d_in[0];
    const int*   lens   = (const int*)  d_in[1];
    const float* w_qkv  = (const float*)d_in[2];
    const float* b_qkv  = (const float*)d_in[3];
    const float* w_proj = (const float*)d_in[4];
    const float* b_proj = (const float*)d_in[5];
    const float* ln1_g  = (const float*)d_in[6];
    const float* ln1_b  = (const float*)d_in[7];
    const float* w_fc   = (const float*)d_in[8];
    const float* b_fc   = (const float*)d_in[9];
    const float* w_out  = (const float*)d_in[10];
    const float* b_out  = (const float*)d_in[11];
    const float* ln2_g  = (const float*)d_in[12];
    const float* ln2_b  = (const float*)d_in[13];

    if (ws_size < 51904512) return;  // -> validation mismatch, not a crash

    char* ws = (char*)d_ws;
    unsigned short* qkvh  = (unsigned short*)(ws + 0);           // [4096,2304]
    unsigned short* xh    = (unsigned short*)(ws + 18874368);    // [4096,768]
    unsigned short* ah    = xh;                                  // attn out (xh dead)
    float*          projo = (float*)(ws + 0);                    // [4096,768] fp32
    unsigned short* fH    = (unsigned short*)(ws + 0);           // [4096,3072]
    unsigned short* nh    = (unsigned short*)(ws + 25165824);    // [4096,768]
    unsigned short* nl    = (unsigned short*)(ws + 31457280);
    unsigned short* wqkvT = (unsigned short*)(ws + 37748736);
    unsigned short* wprojT= (unsigned short*)(ws + 41287680);
    unsigned short* wfcT  = (unsigned short*)(ws + 42467328);
    unsigned short* woutT = (unsigned short*)(ws + 47185920);
    float*          mbuf  = (float*)d_out;

    const dim3 blk(256);
    const dim3 blk512(512);

    // 0) fused prepare: x cast + all weight transposes
    prepare_kernel<<<dim3(6528), blk, 0, stream>>>(
        x, w_qkv, w_proj, w_fc, w_out, xh, wqkvT, wprojT, wfcT, woutT);

    // 1) qkv = x @ w_qkv + b_qkv -> bf16   (8-phase 256², 144 blocks)
    gemm256p8<3><<<dim3((D3 / 256) * 16), blk512, 0, stream>>>(
        xh, wqkvT, b_qkv, nullptr, qkvh, D3, Dc);

    // 2) attention -> ah (bf16)
    flash_attn_bf16<<<dim3(Bc * Hc * (Tc / 64)), blk, 0, stream>>>(qkvh, lens, ah);

    // 3) proj: projo = a @ w_proj + b_proj (fp32)   (8-phase 256², 48 blocks)
    gemm256p8<0><<<dim3((Dc / 256) * 16), blk512, 0, stream>>>(
        ah, wprojT, b_proj, projo, nullptr, Dc, Dc);

    // 4) n = LN(x + projo) * mask -> (nh, nl)
    ln_split_kernel<<<dim3(M_ROWS), blk, 0, stream>>>(x, projo, ln1_g, ln1_b, lens, nh, nl);

    // 5) fc: fH = bf16(gelu(n @ w_fc + b_fc))   (8-phase 256², 192 blocks)
    gemm256p8<1><<<dim3((D4 / 256) * 16), blk512, 0, stream>>>(
        nh, wfcT, b_fc, nullptr, fH, D4, Dc);

    // 6) m = fH @ w_out + b_out -> d_out (fp32), K=3072  (8-phase 256², 48 blocks)
    gemm256p8<0><<<dim3((Dc / 256) * 16), blk512, 0, stream>>>(
        fH, woutT, b_out, mbuf, nullptr, Dc, D4);

    // 7) h = LN((nh+nl) + m) * mask -> d_out (in-place)
    ln2_kernel<<<dim3(M_ROWS), blk, 0, stream>>>(nh, nl, mbuf, ln2_g, ln2_b, lens,
                                                 (float*)d_out);
}

// Round 6
// 326.582 us; speedup vs baseline: 1.1837x; 1.1837x over previous
//
#include <hip/hip_runtime.h>
#include <hip/hip_bf16.h>
#include <math.h>

// Problem constants
constexpr int Bc  = 2;
constexpr int Tc  = 2048;
constexpr int Dc  = 768;
constexpr int Hc  = 12;
constexpr int DHc = 64;
constexpr int M_ROWS = Bc * Tc;        // 4096
constexpr int D3  = 3 * Dc;            // 2304
constexpr int D4  = 4 * Dc;            // 3072
constexpr int HT  = Bc * Hc * Tc;      // 49152 (l-partial plane)

typedef __attribute__((ext_vector_type(8))) short short8;   // 8 bf16 (4 VGPRs)
typedef __attribute__((ext_vector_type(4))) float f32x4;    // MFMA acc

__device__ __forceinline__ unsigned short f2bf(float v) {
    union { __hip_bfloat16 b; unsigned short u; } cv;
    cv.b = __float2bfloat16(v);
    return cv.u;
}
__device__ __forceinline__ float bf2f(unsigned short u) {
    union { __hip_bfloat16 b; unsigned short u; } cv;
    cv.u = u;
    return __bfloat162float(cv.b);
}
__device__ __forceinline__ void bsplit(float v, unsigned short& h, unsigned short& l) {
    h = f2bf(v);
    l = f2bf(v - bf2f(h));
}

__device__ __forceinline__ float gelu_f(float x) {
    const float c = 0.79788456080286535588f; // sqrt(2/pi)
    return 0.5f * x * (1.0f + tanhf(c * (x + 0.044715f * x * x * x)));
}

// Async global->LDS, 16B per lane (LDS dest = wave-uniform base + lane*16).
__device__ __forceinline__ void glds16(const unsigned short* g, unsigned short* l) {
    __builtin_amdgcn_global_load_lds(
        (const __attribute__((address_space(1))) void*)g,
        (__attribute__((address_space(3))) void*)l, 16, 0, 0);
}

// ---------------------------------------------------------------------------
// Fused prepare: x cast + all 4 weight transpose-casts in ONE dispatch.
// ---------------------------------------------------------------------------
__device__ __forceinline__ void tcast8(
    const float* __restrict__ w, int ldw,
    unsigned short* __restrict__ th, int K, int N, int idx)
{
    const int n  = idx % N;
    const int k0 = (idx / N) * 8;
    unsigned short hv[8];
#pragma unroll
    for (int j = 0; j < 8; ++j)
        hv[j] = f2bf(w[(size_t)(k0 + j) * ldw + n]);
    const size_t o = (size_t)n * K + k0;
    *(ushort4*)(th + o)     = make_ushort4(hv[0], hv[1], hv[2], hv[3]);
    *(ushort4*)(th + o + 4) = make_ushort4(hv[4], hv[5], hv[6], hv[7]);
}

__global__ __launch_bounds__(256) void prepare_kernel(
    const float* __restrict__ x,
    const float* __restrict__ w_qkv, const float* __restrict__ w_proj,
    const float* __restrict__ w_fc,  const float* __restrict__ w_out,
    unsigned short* __restrict__ xh,
    unsigned short* __restrict__ wqkvT, unsigned short* __restrict__ wprojT,
    unsigned short* __restrict__ wfcT,  unsigned short* __restrict__ woutT)
{
    int id = blockIdx.x * 256 + threadIdx.x;
    if (id < 786432) {
        const float4 v = *(const float4*)(x + (size_t)id * 4);
        *(ushort4*)(xh + (size_t)id * 4) =
            make_ushort4(f2bf(v.x), f2bf(v.y), f2bf(v.z), f2bf(v.w));
        return;
    }
    id -= 786432;
    if (id < 221184) { tcast8(w_qkv, D3, wqkvT, Dc, D3, id); return; }
    id -= 221184;
    if (id < 73728)  { tcast8(w_proj, Dc, wprojT, Dc, Dc, id); return; }
    id -= 73728;
    if (id < 294912) { tcast8(w_fc, D4, wfcT, Dc, D4, id); return; }
    id -= 294912;
    tcast8(w_out, Dc, woutT, D4, Dc, id);
}

// ---------------------------------------------------------------------------
// R0-proven bf16 MFMA GEMM, BK=64, single-buffered. Best measured structure
// this session: latency hiding comes from block residency (TM=64 -> 24 KB
// LDS -> 6 blocks/CU when the grid provides them), not intra-block
// pipelining (R1/R2/R5 all regressed). Tile TM x 128, 256 thr = 4 waves.
// LDS rows 64 shorts contiguous (glds16 req); 16B chunks XOR-swizzled on
// the GLOBAL side (phys chunk p of row r = p^(r&7)); frag reads un-swizzle.
// MODE: 0 = fp32 out (+bias) | 1 = gelu -> bf16 out (+bias) | 3 = bf16 out
// ---------------------------------------------------------------------------
template <int TM, int MODE>
__global__ __launch_bounds__(256) void gemm_bf16(
    const unsigned short* __restrict__ A,
    const unsigned short* __restrict__ B,
    const float* __restrict__ bias,
    float* __restrict__ C, unsigned short* __restrict__ Cb,
    int M, int N, int K)
{
    constexpr int MT = TM / 32;              // m-tiles per wave (4 or 2)
    __shared__ unsigned short Ash[TM * 64];
    __shared__ unsigned short Bsh[128 * 64];

    const int tid  = threadIdx.x;
    const int n0   = blockIdx.x * 128;
    const int m0   = blockIdx.y * TM;
    const int wave = tid >> 6;
    const int lane = tid & 63;
    const int wm   = (wave >> 1) * (TM / 2);
    const int wn   = (wave & 1) * 64;
    const int lrow = lane & 15;
    const int quad = lane >> 4;
    const int swz  = lrow & 7;               // frag-read row swizzle key

    f32x4 acc[MT][4];
    const f32x4 zero = {0.f, 0.f, 0.f, 0.f};
#pragma unroll
    for (int i = 0; i < MT; ++i)
#pragma unroll
        for (int j = 0; j < 4; ++j) acc[i][j] = zero;

    // staging: one glds16 issue covers 8 rows x 128 B. lane -> (row, chunk).
    const int l8r  = lane >> 3;              // 0..7 row within issue
    const int csel = ((lane & 7) ^ l8r) * 8; // swizzled global chunk (shorts)

    for (int ks = 0; ks < K; ks += 64) {
        __syncthreads();
#pragma unroll
        for (int j = 0; j < TM / 32; ++j) {
            const int rbase = wave * (TM / 4) + j * 8;
            const size_t g = (size_t)(m0 + rbase + l8r) * K + ks + csel;
            glds16(A + g, &Ash[rbase * 64]);
        }
#pragma unroll
        for (int j = 0; j < 4; ++j) {
            const int rbase = wave * 32 + j * 8;
            const size_t g = (size_t)(n0 + rbase + l8r) * K + ks + csel;
            glds16(B + g, &Bsh[rbase * 64]);
        }
        __syncthreads();

#pragma unroll
        for (int kk = 0; kk < 2; ++kk) {
            short8 fa[MT], fb[4];
            const int cl = kk * 4 + quad;    // logical chunk
            const int pc = (cl ^ swz) * 8;   // physical chunk offset (shorts)
#pragma unroll
            for (int t = 0; t < MT; ++t)
                fa[t] = *(const short8*)&Ash[(wm + t * 16 + lrow) * 64 + pc];
#pragma unroll
            for (int t = 0; t < 4; ++t)
                fb[t] = *(const short8*)&Bsh[(wn + t * 16 + lrow) * 64 + pc];
#pragma unroll
            for (int mt = 0; mt < MT; ++mt)
#pragma unroll
                for (int nt = 0; nt < 4; ++nt)
                    acc[mt][nt] = __builtin_amdgcn_mfma_f32_16x16x32_bf16(
                        fa[mt], fb[nt], acc[mt][nt], 0, 0, 0);
        }
    }

#pragma unroll
    for (int mt = 0; mt < MT; ++mt) {
        const int rowb = m0 + wm + mt * 16 + quad * 4;
#pragma unroll
        for (int nt = 0; nt < 4; ++nt) {
            const int col = n0 + wn + nt * 16 + lrow;
            const float bv = bias[col];
#pragma unroll
            for (int r = 0; r < 4; ++r) {
                const size_t ci = (size_t)(rowb + r) * N + col;
                if (MODE == 0) {
                    C[ci] = acc[mt][nt][r] + bv;
                } else if (MODE == 1) {
                    Cb[ci] = f2bf(gelu_f(acc[mt][nt][r] + bv));
                } else { // MODE 3
                    Cb[ci] = f2bf(acc[mt][nt][r] + bv);
                }
            }
        }
    }
}

// ---------------------------------------------------------------------------
// bf16 MFMA flash attention, SPLIT-K2 (v6):
// The v4 inner loop (proven 71-73 µs) was grid-limited: 768 blocks = 3
// blocks/CU = 28% occupancy with MFMA 14% / VALU 35% (latency-bound).
// Split each (b,h,qtile)'s K-range into two halves -> 1536 blocks
// (5 blocks/CU, LDS-capped). Each half writes UNNORMALIZED O-partial (fp32)
// and l-partial; attn_combine does (O0+O1)/(l0+l1), with l==0 -> 0 (also
// handles masked q-rows exactly, since those get l=0 from both halves).
// Numerics per half identical to v4 (exp2 trick, Vt swizzle, len masking).
// LDS 27.6 KB, one block = 4 waves per (half, b, h, 64-query tile).
// ---------------------------------------------------------------------------
constexpr int KS  = 72;  // K/V LDS row stride (shorts): 144B rows, 16B-aligned
constexpr int PS2 = 72;  // P LDS row stride (shorts)

__global__ __launch_bounds__(256) void flash_attn_split(
    const unsigned short* __restrict__ qkv,
    const int* __restrict__ lengths,
    float* __restrict__ O0, float* __restrict__ O1,
    float* __restrict__ lp)                  // [2][B][H][T]
{
    __shared__ unsigned short Kh[64 * KS];
    __shared__ unsigned short Vt[64 * KS];    // V^T: [d][k], chunk-swizzled
    __shared__ unsigned short PfU[64 * PS2];  // P bf16, wave-private strips

    const int tid  = threadIdx.x;
    const int wave = tid >> 6;
    const int lane = tid & 63;
    const int m    = lane & 15;
    const int quad = lane >> 4;

    const int nqt  = Tc / 64;                 // 32
    const int nblk = Bc * Hc * nqt;           // 768
    const int half = blockIdx.x / nblk;       // 0 or 1
    const int bid  = blockIdx.x % nblk;
    const int qt  = bid % nqt;
    const int bh  = bid / nqt;
    const int hh  = bh % Hc;
    const int b   = bh / Hc;
    const int len = lengths[b];
    const int q0  = qt * 64;
    const size_t rs = (size_t)D3;
    const unsigned short* base = qkv + (size_t)b * Tc * rs;
    const int qcol = hh * DHc;
    const int kcol = Dc + hh * DHc;
    const int vcol = 2 * Dc + hh * DHc;

    float* __restrict__ Op = half ? O1 : O0;
    const int lbase = half * HT + (b * Hc + hh) * Tc;

    // ---- q-tile fully masked: write zero partials, done ----
    if (q0 >= len) {
#pragma unroll
        for (int r = 0; r < 4; ++r) {
            const int qrow = q0 + wave * 16 + quad * 4 + r;
            const size_t ob = (size_t)(b * Tc + qrow) * Dc + hh * DHc + m;
#pragma unroll
            for (int nt = 0; nt < 4; ++nt) Op[ob + nt * 16] = 0.f;
            if (m == 0) lp[lbase + qrow] = 0.f;
        }
        return;
    }

    const int ktEnd = (min(len, Tc) + 63) >> 6;   // valid K tiles
    const int kt0 = (half * ktEnd) >> 1;
    const int kt1 = ((half + 1) * ktEnd) >> 1;

    // ---- preload Q fragments (A-layout), pre-scaled by log2(e) ----
    short8 Qf[2];
#pragma unroll
    for (int ch = 0; ch < 2; ++ch) {
        const size_t ga = (size_t)(q0 + wave * 16 + m) * rs + qcol + ch * 32 + quad * 8;
        const short8 q8 = *(const short8*)&base[ga];
        short8 qs;
#pragma unroll
        for (int j = 0; j < 8; ++j)
            qs[j] = (short)f2bf(bf2f((unsigned short)q8[j]) * 1.44269504088896f);
        Qf[ch] = qs;
    }

    f32x4 Oacc[4];
    const f32x4 zero = {0.f, 0.f, 0.f, 0.f};
#pragma unroll
    for (int nt = 0; nt < 4; ++nt) Oacc[nt] = zero;
    float lrow[4] = {0.f, 0.f, 0.f, 0.f};     // per-lane partial row sums

    // staging maps
    const int kr0 = tid >> 3,          kc0 = (tid & 7) * 8;          // rows 0..31
    const int kr1 = (tid + 256) >> 3,  kc1 = ((tid + 256) & 7) * 8;  // rows 32..63
    const int pk  = (tid >> 4) * 4;      // V patch: k-base (0,4,8,12)
    const int pd  = (tid & 15) * 4;      // V patch: d-base (0..60)
    // Vt swizzle: phys chunk = (k>>3) ^ ((d>>2)&7); uniform per thread-patch.
    const int vswz = ((pk >> 3) ^ ((pd >> 2) & 7)) * 8 + (pk & 7);

    // prefetch registers: tile kt0
    short8  pK0, pK1;
    ushort4 pV0, pV1, pV2, pV3;
    {
        const int nb = kt0 * 64;
        pK0 = *(const short8*)&base[(size_t)(nb + kr0) * rs + kcol + kc0];
        pK1 = *(const short8*)&base[(size_t)(nb + kr1) * rs + kcol + kc1];
        pV0 = *(const ushort4*)&base[(size_t)(nb + pk + 0) * rs + vcol + pd];
        pV1 = *(const ushort4*)&base[(size_t)(nb + pk + 1) * rs + vcol + pd];
        pV2 = *(const ushort4*)&base[(size_t)(nb + pk + 2) * rs + vcol + pd];
        pV3 = *(const ushort4*)&base[(size_t)(nb + pk + 3) * rs + vcol + pd];
    }

    for (int kt = kt0; kt < kt1; ++kt) {
        const int kbase = kt * 64;
        __syncthreads();   // previous iter done reading Kh/Vt

        // ---- stage prefetched K/V to LDS (Vt chunk-swizzled) ----
        *(short8*)&Kh[kr0 * KS + kc0] = pK0;
        *(short8*)&Kh[kr1 * KS + kc1] = pK1;
        *(ushort4*)&Vt[(pd + 0) * KS + vswz] = make_ushort4(pV0.x, pV1.x, pV2.x, pV3.x);
        *(ushort4*)&Vt[(pd + 1) * KS + vswz] = make_ushort4(pV0.y, pV1.y, pV2.y, pV3.y);
        *(ushort4*)&Vt[(pd + 2) * KS + vswz] = make_ushort4(pV0.z, pV1.z, pV2.z, pV3.z);
        *(ushort4*)&Vt[(pd + 3) * KS + vswz] = make_ushort4(pV0.w, pV1.w, pV2.w, pV3.w);
        __syncthreads();

        // ---- issue loads for tile kt+1 (hidden behind compute below) ----
        if (kt + 1 < kt1) {
            const int nb = kbase + 64;
            pK0 = *(const short8*)&base[(size_t)(nb + kr0) * rs + kcol + kc0];
            pK1 = *(const short8*)&base[(size_t)(nb + kr1) * rs + kcol + kc1];
            pV0 = *(const ushort4*)&base[(size_t)(nb + pk + 0) * rs + vcol + pd];
            pV1 = *(const ushort4*)&base[(size_t)(nb + pk + 1) * rs + vcol + pd];
            pV2 = *(const ushort4*)&base[(size_t)(nb + pk + 2) * rs + vcol + pd];
            pV3 = *(const ushort4*)&base[(size_t)(nb + pk + 3) * rs + vcol + pd];
        }

        // ---- S' = (Q*log2e) · K^T ----
        f32x4 S4[4];
#pragma unroll
        for (int nt = 0; nt < 4; ++nt) S4[nt] = zero;
#pragma unroll
        for (int ch = 0; ch < 2; ++ch)
#pragma unroll
            for (int nt = 0; nt < 4; ++nt) {
                const short8 k8 = *(const short8*)&Kh[(nt * 16 + m) * KS + ch * 32 + quad * 8];
                S4[nt] = __builtin_amdgcn_mfma_f32_16x16x32_bf16(Qf[ch], k8, S4[nt], 0, 0, 0);
            }

        // ---- mask invalid keys (exp2(-1e30) underflows to exact 0) ----
        if (kbase + 64 > len) {
#pragma unroll
            for (int nt = 0; nt < 4; ++nt)
                if (kbase + nt * 16 + m >= len) {
#pragma unroll
                    for (int r = 0; r < 4; ++r) S4[nt][r] = -1e30f;
                }
        }

        // ---- p = exp2(S'); accumulate partial l; store P (bf16) ----
#pragma unroll
        for (int nt = 0; nt < 4; ++nt)
#pragma unroll
            for (int r = 0; r < 4; ++r) {
                const float p = __builtin_amdgcn_exp2f(S4[nt][r]);
                lrow[r] += p;
                PfU[(wave * 16 + quad * 4 + r) * PS2 + nt * 16 + m] = f2bf(p);
            }

        // ---- O += P · V (Vt read un-swizzled per (nt,ch,quad,m)) ----
#pragma unroll
        for (int ch = 0; ch < 2; ++ch) {
            const short8 P8 = *(const short8*)&PfU[(wave * 16 + m) * PS2 + ch * 32 + quad * 8];
#pragma unroll
            for (int nt = 0; nt < 4; ++nt) {
                const int pchunk = ((ch * 4 + quad) ^ ((nt * 4 + (m >> 2)) & 7)) * 8;
                const short8 v8 = *(const short8*)&Vt[(nt * 16 + m) * KS + pchunk];
                Oacc[nt] = __builtin_amdgcn_mfma_f32_16x16x32_bf16(P8, v8, Oacc[nt], 0, 0, 0);
            }
        }
    }

    // ---- row-sum reduction over the 16 m-lanes ----
#pragma unroll
    for (int r = 0; r < 4; ++r) {
#pragma unroll
        for (int sh = 8; sh >= 1; sh >>= 1)
            lrow[r] += __shfl_xor(lrow[r], sh);
    }

    // ---- epilogue: write UNNORMALIZED partials + l-partials ----
#pragma unroll
    for (int r = 0; r < 4; ++r) {
        const int qrow = q0 + wave * 16 + quad * 4 + r;
        const size_t ob = (size_t)(b * Tc + qrow) * Dc + hh * DHc + m;
        if (qrow < len) {
#pragma unroll
            for (int nt = 0; nt < 4; ++nt)
                Op[ob + nt * 16] = Oacc[nt][r];
            if (m == 0) lp[lbase + qrow] = lrow[r];
        } else {
#pragma unroll
            for (int nt = 0; nt < 4; ++nt)
                Op[ob + nt * 16] = 0.f;
            if (m == 0) lp[lbase + qrow] = 0.f;
        }
    }
}

// ---------------------------------------------------------------------------
// attn_combine: ah = bf16((O0+O1) / (l0+l1)), l==0 -> 0.
// One block per row, 3 cols/thread. ~31 MB traffic ≈ 6-8 µs.
// ---------------------------------------------------------------------------
__global__ __launch_bounds__(256) void attn_combine(
    const float* __restrict__ O0, const float* __restrict__ O1,
    const float* __restrict__ lp,
    unsigned short* __restrict__ ah)
{
    const int row = blockIdx.x;
    const int b = row / Tc, t = row % Tc;
    const int tid = threadIdx.x;
    const size_t basei = (size_t)row * Dc;
#pragma unroll
    for (int j = 0; j < 3; ++j) {
        const int col = tid + j * 256;
        const int h = col >> 6;
        const float l = lp[(b * Hc + h) * Tc + t] + lp[HT + (b * Hc + h) * Tc + t];
        const float o = O0[basei + col] + O1[basei + col];
        ah[basei + col] = (l > 0.f) ? f2bf(o / l) : (unsigned short)0;
    }
}

// ---------------------------------------------------------------------------
// LN1: (outh,outl) = split_bf16(LN(X + Y) * mask). X,Y fp32.
// ---------------------------------------------------------------------------
__global__ __launch_bounds__(256) void ln_split_kernel(
    const float* __restrict__ X, const float* __restrict__ Y,
    const float* __restrict__ g, const float* __restrict__ beta,
    const int* __restrict__ lengths,
    unsigned short* __restrict__ outh, unsigned short* __restrict__ outl)
{
    __shared__ float red[4];
    const int row = blockIdx.x;
    const int b = row / Tc, t = row % Tc;
    const int len = lengths[b];
    const size_t basei = (size_t)row * Dc;
    const int tid = threadIdx.x;

    if (t >= len) {
        for (int j = tid; j < Dc; j += 256) { outh[basei + j] = 0; outl[basei + j] = 0; }
        return;
    }

    float v[3];
    float s = 0.f;
#pragma unroll
    for (int j = 0; j < 3; ++j) {
        int idx = tid + j * 256;
        v[j] = X[basei + idx] + Y[basei + idx];
        s += v[j];
    }
    const int lane = tid % 64, wid = tid / 64;
#pragma unroll
    for (int sh = 32; sh >= 1; sh >>= 1) s += __shfl_xor(s, sh);
    if (lane == 0) red[wid] = s;
    __syncthreads();
    s = red[0] + red[1] + red[2] + red[3];
    const float mu = s * (1.0f / Dc);

    float vs = 0.f;
#pragma unroll
    for (int j = 0; j < 3; ++j) { float dv = v[j] - mu; vs += dv * dv; }
    __syncthreads();
#pragma unroll
    for (int sh = 32; sh >= 1; sh >>= 1) vs += __shfl_xor(vs, sh);
    if (lane == 0) red[wid] = vs;
    __syncthreads();
    vs = red[0] + red[1] + red[2] + red[3];
    const float rstd = rsqrtf(vs * (1.0f / Dc) + 1e-5f);

#pragma unroll
    for (int j = 0; j < 3; ++j) {
        int idx = tid + j * 256;
        const float ov = (v[j] - mu) * rstd * g[idx] + beta[idx];
        unsigned short hh, ll;
        bsplit(ov, hh, ll);
        outh[basei + idx] = hh;
        outl[basei + idx] = ll;
    }
}

// ---------------------------------------------------------------------------
// LN2: out = LN((Xh+Xl) + Y) * mask, fp32 out. Y and out may alias (in-place).
// ---------------------------------------------------------------------------
__global__ __launch_bounds__(256) void ln2_kernel(
    const unsigned short* __restrict__ Xh, const unsigned short* __restrict__ Xl,
    const float* Y,
    const float* __restrict__ g, const float* __restrict__ beta,
    const int* __restrict__ lengths, float* out)
{
    __shared__ float red[4];
    const int row = blockIdx.x;
    const int b = row / Tc, t = row % Tc;
    const int len = lengths[b];
    const size_t basei = (size_t)row * Dc;
    const int tid = threadIdx.x;

    if (t >= len) {
        for (int j = tid; j < Dc; j += 256) out[basei + j] = 0.f;
        return;
    }

    float v[3];
    float s = 0.f;
#pragma unroll
    for (int j = 0; j < 3; ++j) {
        int idx = tid + j * 256;
        v[j] = bf2f(Xh[basei + idx]) + bf2f(Xl[basei + idx]) + Y[basei + idx];
        s += v[j];
    }
    const int lane = tid % 64, wid = tid / 64;
#pragma unroll
    for (int sh = 32; sh >= 1; sh >>= 1) s += __shfl_xor(s, sh);
    if (lane == 0) red[wid] = s;
    __syncthreads();
    s = red[0] + red[1] + red[2] + red[3];
    const float mu = s * (1.0f / Dc);

    float vs = 0.f;
#pragma unroll
    for (int j = 0; j < 3; ++j) { float dv = v[j] - mu; vs += dv * dv; }
    __syncthreads();
#pragma unroll
    for (int sh = 32; sh >= 1; sh >>= 1) vs += __shfl_xor(vs, sh);
    if (lane == 0) red[wid] = vs;
    __syncthreads();
    vs = red[0] + red[1] + red[2] + red[3];
    const float rstd = rsqrtf(vs * (1.0f / Dc) + 1e-5f);

#pragma unroll
    for (int j = 0; j < 3; ++j) {
        int idx = tid + j * 256;
        out[basei + idx] = (v[j] - mu) * rstd * g[idx] + beta[idx];
    }
}

// ---------------------------------------------------------------------------
// Workspace plan (bytes; peak 51,904,512):
//   [0, 18.87M)        : qkvh -> projo fp32 [0,12.58M) -> fH head
//   [18.87M, 25.17M)   : xh -> ah -> fH tail  (fH = [0,25.17M) [4096,3072])
//   [25.17M, 31.46M)   : nh | [31.46M, 37.75M) : nl
//        (nh+nl span doubles as attn O1 fp32 [4096,768] — dead until LN1)
//   [37.75M, 41.29M)   : wqkvT (dead after qkv -> attn l-partials [2][49152])
//   [41.29M, 42.47M)   : wprojT
//   [42.47M, 47.19M)   : wfcT  | [47.19M, 51.91M) : woutT
//   d_out doubles as attn O0 fp32 (dead until step 6).
// ---------------------------------------------------------------------------
extern "C" void kernel_launch(void* const* d_in, const int* in_sizes, int n_in,
                              void* d_out, int out_size, void* d_ws, size_t ws_size,
                              hipStream_t stream)
{
    const float* x      = (const float*)d_in[0];
    const int*   lens   = (const int*)  d_in[1];
    const float* w_qkv  = (const float*)d_in[2];
    const float* b_qkv  = (const float*)d_in[3];
    const float* w_proj = (const float*)d_in[4];
    const float* b_proj = (const float*)d_in[5];
    const float* ln1_g  = (const float*)d_in[6];
    const float* ln1_b  = (const float*)d_in[7];
    const float* w_fc   = (const float*)d_in[8];
    const float* b_fc   = (const float*)d_in[9];
    const float* w_out  = (const float*)d_in[10];
    const float* b_out  = (const float*)d_in[11];
    const float* ln2_g  = (const float*)d_in[12];
    const float* ln2_b  = (const float*)d_in[13];

    if (ws_size < 51904512) return;  // -> validation mismatch, not a crash

    char* ws = (char*)d_ws;
    unsigned short* qkvh  = (unsigned short*)(ws + 0);           // [4096,2304]
    unsigned short* xh    = (unsigned short*)(ws + 18874368);    // [4096,768]
    unsigned short* ah    = xh;                                  // attn out (xh dead)
    float*          projo = (float*)(ws + 0);                    // [4096,768] fp32
    unsigned short* fH    = (unsigned short*)(ws + 0);           // [4096,3072]
    unsigned short* nh    = (unsigned short*)(ws + 25165824);    // [4096,768]
    unsigned short* nl    = (unsigned short*)(ws + 31457280);
    unsigned short* wqkvT = (unsigned short*)(ws + 37748736);
    unsigned short* wprojT= (unsigned short*)(ws + 41287680);
    unsigned short* wfcT  = (unsigned short*)(ws + 42467328);
    unsigned short* woutT = (unsigned short*)(ws + 47185920);
    float*          mbuf  = (float*)d_out;

    // attn split-K2 partial buffers (all aliases of dead regions):
    float* O0 = (float*)d_out;                 // [4096,768] fp32, dead till step 6
    float* O1 = (float*)(ws + 25165824);       // nh+nl span, dead till step 4
    float* lp = (float*)(ws + 37748736);       // wqkvT slot, dead after step 1

    const dim3 blk(256);

    // 0) fused prepare: x cast + all weight transposes
    prepare_kernel<<<dim3(6528), blk, 0, stream>>>(
        x, w_qkv, w_proj, w_fc, w_out, xh, wqkvT, wprojT, wfcT, woutT);

    // 1) qkv = x @ w_qkv + b_qkv -> bf16  (TM=64: 1152 blocks, 4.5/CU)
    gemm_bf16<64, 3><<<dim3(D3 / 128, M_ROWS / 64), blk, 0, stream>>>(
        xh, wqkvT, b_qkv, nullptr, qkvh, M_ROWS, D3, Dc);

    // 2) attention split-K2 -> partials (1536 blocks, 5/CU LDS-capped)
    flash_attn_split<<<dim3(2 * Bc * Hc * (Tc / 64)), blk, 0, stream>>>(
        qkvh, lens, O0, O1, lp);

    // 2.5) combine -> ah (bf16)
    attn_combine<<<dim3(M_ROWS), blk, 0, stream>>>(O0, O1, lp, ah);

    // 3) proj: projo = a @ w_proj + b_proj (fp32)
    gemm_bf16<64, 0><<<dim3(Dc / 128, M_ROWS / 64), blk, 0, stream>>>(
        ah, wprojT, b_proj, projo, nullptr, M_ROWS, Dc, Dc);

    // 4) n = LN(x + projo) * mask -> (nh, nl)
    ln_split_kernel<<<dim3(M_ROWS), blk, 0, stream>>>(x, projo, ln1_g, ln1_b, lens, nh, nl);

    // 5) fc: fH = bf16(gelu(n @ w_fc + b_fc))  (TM=64: 1536 blocks, 6/CU)
    gemm_bf16<64, 1><<<dim3(D4 / 128, M_ROWS / 64), blk, 0, stream>>>(
        nh, wfcT, b_fc, nullptr, fH, M_ROWS, D4, Dc);

    // 6) m = fH @ w_out + b_out -> d_out (fp32), K=3072
    gemm_bf16<64, 0><<<dim3(Dc / 128, M_ROWS / 64), blk, 0, stream>>>(
        fH, woutT, b_out, mbuf, nullptr, M_ROWS, Dc, D4);

    // 7) h = LN((nh+nl) + m) * mask -> d_out (in-place)
    ln2_kernel<<<dim3(M_ROWS), blk, 0, stream>>>(nh, nl, mbuf, ln2_g, ln2_b, lens,
                                                 (float*)d_out);
}

// Round 7
// 314.824 us; speedup vs baseline: 1.2279x; 1.0373x over previous
//
#include <hip/hip_runtime.h>
#include <hip/hip_bf16.h>
#include <math.h>

// Problem constants
constexpr int Bc  = 2;
constexpr int Tc  = 2048;
constexpr int Dc  = 768;
constexpr int Hc  = 12;
constexpr int DHc = 64;
constexpr int M_ROWS = Bc * Tc;        // 4096
constexpr int D3  = 3 * Dc;            // 2304
constexpr int D4  = 4 * Dc;            // 3072

typedef __attribute__((ext_vector_type(8))) short short8;   // 8 bf16 (4 VGPRs)
typedef __attribute__((ext_vector_type(4))) float f32x4;    // MFMA acc

__device__ __forceinline__ unsigned short f2bf(float v) {
    union { __hip_bfloat16 b; unsigned short u; } cv;
    cv.b = __float2bfloat16(v);
    return cv.u;
}
__device__ __forceinline__ float bf2f(unsigned short u) {
    union { __hip_bfloat16 b; unsigned short u; } cv;
    cv.u = u;
    return __bfloat162float(cv.b);
}
__device__ __forceinline__ void bsplit(float v, unsigned short& h, unsigned short& l) {
    h = f2bf(v);
    l = f2bf(v - bf2f(h));
}

__device__ __forceinline__ float gelu_f(float x) {
    const float c = 0.79788456080286535588f; // sqrt(2/pi)
    return 0.5f * x * (1.0f + tanhf(c * (x + 0.044715f * x * x * x)));
}

// Async global->LDS, 16B per lane (LDS dest = wave-uniform base + lane*16).
__device__ __forceinline__ void glds16(const unsigned short* g, unsigned short* l) {
    __builtin_amdgcn_global_load_lds(
        (const __attribute__((address_space(1))) void*)g,
        (__attribute__((address_space(3))) void*)l, 16, 0, 0);
}

// ---------------------------------------------------------------------------
// Fused prepare: x cast + all 4 weight transpose-casts in ONE dispatch.
// ---------------------------------------------------------------------------
__device__ __forceinline__ void tcast8(
    const float* __restrict__ w, int ldw,
    unsigned short* __restrict__ th, int K, int N, int idx)
{
    const int n  = idx % N;
    const int k0 = (idx / N) * 8;
    unsigned short hv[8];
#pragma unroll
    for (int j = 0; j < 8; ++j)
        hv[j] = f2bf(w[(size_t)(k0 + j) * ldw + n]);
    const size_t o = (size_t)n * K + k0;
    *(ushort4*)(th + o)     = make_ushort4(hv[0], hv[1], hv[2], hv[3]);
    *(ushort4*)(th + o + 4) = make_ushort4(hv[4], hv[5], hv[6], hv[7]);
}

__global__ __launch_bounds__(256) void prepare_kernel(
    const float* __restrict__ x,
    const float* __restrict__ w_qkv, const float* __restrict__ w_proj,
    const float* __restrict__ w_fc,  const float* __restrict__ w_out,
    unsigned short* __restrict__ xh,
    unsigned short* __restrict__ wqkvT, unsigned short* __restrict__ wprojT,
    unsigned short* __restrict__ wfcT,  unsigned short* __restrict__ woutT)
{
    int id = blockIdx.x * 256 + threadIdx.x;
    if (id < 786432) {
        const float4 v = *(const float4*)(x + (size_t)id * 4);
        *(ushort4*)(xh + (size_t)id * 4) =
            make_ushort4(f2bf(v.x), f2bf(v.y), f2bf(v.z), f2bf(v.w));
        return;
    }
    id -= 786432;
    if (id < 221184) { tcast8(w_qkv, D3, wqkvT, Dc, D3, id); return; }
    id -= 221184;
    if (id < 73728)  { tcast8(w_proj, Dc, wprojT, Dc, Dc, id); return; }
    id -= 73728;
    if (id < 294912) { tcast8(w_fc, D4, wfcT, Dc, D4, id); return; }
    id -= 294912;
    tcast8(w_out, Dc, woutT, D4, Dc, id);
}

// ---------------------------------------------------------------------------
// R0-proven bf16 MFMA GEMM, BK=64, single-buffered, now TN-parameterized.
// TN=128 reproduces the original kernel exactly. TN=64 halves the column
// tile so small-N GEMMs (proj/out: N=768) get 2x the blocks (384 -> 768,
// 1.5 -> 3 blocks/CU) — the measured bottleneck for those two dispatches
// was grid starvation (31% occupancy), not the inner loop.
// Tile TM x TN, 256 thr = 4 waves (2m x 2n). LDS rows 64 shorts contiguous
// (glds16 req); 16B chunks XOR-swizzled on the GLOBAL side (phys chunk p of
// row r = p^(r&7)); frag reads un-swizzle with one XOR.
// MODE: 0 = fp32 out (+bias) | 1 = gelu -> bf16 out (+bias) | 3 = bf16 out
// ---------------------------------------------------------------------------
template <int TM, int TN, int MODE>
__global__ __launch_bounds__(256) void gemm_bf16(
    const unsigned short* __restrict__ A,
    const unsigned short* __restrict__ B,
    const float* __restrict__ bias,
    float* __restrict__ C, unsigned short* __restrict__ Cb,
    int M, int N, int K)
{
    constexpr int MT = TM / 32;              // m-tiles per wave
    constexpr int NT = TN / 32;              // n-tiles per wave
    __shared__ unsigned short Ash[TM * 64];
    __shared__ unsigned short Bsh[TN * 64];

    const int tid  = threadIdx.x;
    const int n0   = blockIdx.x * TN;
    const int m0   = blockIdx.y * TM;
    const int wave = tid >> 6;
    const int lane = tid & 63;
    const int wm   = (wave >> 1) * (TM / 2);
    const int wn   = (wave & 1) * (TN / 2);
    const int lrow = lane & 15;
    const int quad = lane >> 4;
    const int swz  = lrow & 7;               // frag-read row swizzle key

    f32x4 acc[MT][NT];
    const f32x4 zero = {0.f, 0.f, 0.f, 0.f};
#pragma unroll
    for (int i = 0; i < MT; ++i)
#pragma unroll
        for (int j = 0; j < NT; ++j) acc[i][j] = zero;

    // staging: one glds16 issue covers 8 rows x 128 B. lane -> (row, chunk).
    const int l8r  = lane >> 3;              // 0..7 row within issue
    const int csel = ((lane & 7) ^ l8r) * 8; // swizzled global chunk (shorts)

    for (int ks = 0; ks < K; ks += 64) {
        __syncthreads();
#pragma unroll
        for (int j = 0; j < TM / 32; ++j) {
            const int rbase = wave * (TM / 4) + j * 8;
            const size_t g = (size_t)(m0 + rbase + l8r) * K + ks + csel;
            glds16(A + g, &Ash[rbase * 64]);
        }
#pragma unroll
        for (int j = 0; j < TN / 32; ++j) {
            const int rbase = wave * (TN / 4) + j * 8;
            const size_t g = (size_t)(n0 + rbase + l8r) * K + ks + csel;
            glds16(B + g, &Bsh[rbase * 64]);
        }
        __syncthreads();

#pragma unroll
        for (int kk = 0; kk < 2; ++kk) {
            short8 fa[MT], fb[NT];
            const int cl = kk * 4 + quad;    // logical chunk
            const int pc = (cl ^ swz) * 8;   // physical chunk offset (shorts)
#pragma unroll
            for (int t = 0; t < MT; ++t)
                fa[t] = *(const short8*)&Ash[(wm + t * 16 + lrow) * 64 + pc];
#pragma unroll
            for (int t = 0; t < NT; ++t)
                fb[t] = *(const short8*)&Bsh[(wn + t * 16 + lrow) * 64 + pc];
#pragma unroll
            for (int mt = 0; mt < MT; ++mt)
#pragma unroll
                for (int nt = 0; nt < NT; ++nt)
                    acc[mt][nt] = __builtin_amdgcn_mfma_f32_16x16x32_bf16(
                        fa[mt], fb[nt], acc[mt][nt], 0, 0, 0);
        }
    }

#pragma unroll
    for (int mt = 0; mt < MT; ++mt) {
        const int rowb = m0 + wm + mt * 16 + quad * 4;
#pragma unroll
        for (int nt = 0; nt < NT; ++nt) {
            const int col = n0 + wn + nt * 16 + lrow;
            const float bv = bias[col];
#pragma unroll
            for (int r = 0; r < 4; ++r) {
                const size_t ci = (size_t)(rowb + r) * N + col;
                if (MODE == 0) {
                    C[ci] = acc[mt][nt][r] + bv;
                } else if (MODE == 1) {
                    Cb[ci] = f2bf(gelu_f(acc[mt][nt][r] + bv));
                } else { // MODE 3
                    Cb[ci] = f2bf(acc[mt][nt][r] + bv);
                }
            }
        }
    }
}

// ---------------------------------------------------------------------------
// bf16 MFMA flash attention, v4 (the session's proven best: 70.6-73 µs).
//  - K-loop bounded by len; q-tile early-out when q0 >= len
//  - Q pre-scaled by log2(e); exp2 in the softmax
//  - Vt XOR-swizzle kills staging-write bank conflicts
// One block = 4 waves per (b, h, 64-query tile). LDS 27.6 KB.
// ---------------------------------------------------------------------------
constexpr int KS  = 72;  // K/V LDS row stride (shorts): 144B rows, 16B-aligned
constexpr int PS2 = 72;  // P LDS row stride (shorts)

__global__ __launch_bounds__(256) void flash_attn_bf16(
    const unsigned short* __restrict__ qkv,
    const int* __restrict__ lengths,
    unsigned short* __restrict__ oh)
{
    __shared__ unsigned short Kh[64 * KS];
    __shared__ unsigned short Vt[64 * KS];    // V^T: [d][k], chunk-swizzled
    __shared__ unsigned short PfU[64 * PS2];  // P bf16, wave-private strips

    const int tid  = threadIdx.x;
    const int wave = tid >> 6;
    const int lane = tid & 63;
    const int m    = lane & 15;
    const int quad = lane >> 4;

    const int nqt = Tc / 64;                  // 32
    const int qt  = blockIdx.x % nqt;
    const int bh  = blockIdx.x / nqt;
    const int hh  = bh % Hc;
    const int b   = bh / Hc;
    const int len = lengths[b];
    const int q0  = qt * 64;
    const size_t rs = (size_t)D3;
    const unsigned short* base = qkv + (size_t)b * Tc * rs;
    const int qcol = hh * DHc;
    const int kcol = Dc + hh * DHc;
    const int vcol = 2 * Dc + hh * DHc;

    // ---- q-tile fully masked: write zeros, done ----
    if (q0 >= len) {
#pragma unroll
        for (int r = 0; r < 4; ++r) {
            const int qrow = q0 + wave * 16 + quad * 4 + r;
            const size_t ob = (size_t)(b * Tc + qrow) * Dc + hh * DHc + m;
#pragma unroll
            for (int nt = 0; nt < 4; ++nt) oh[ob + nt * 16] = 0;
        }
        return;
    }

    const int ktEnd = (min(len, Tc) + 63) >> 6;   // skip fully-masked K tiles

    // ---- preload Q fragments (A-layout), pre-scaled by log2(e) ----
    short8 Qf[2];
#pragma unroll
    for (int ch = 0; ch < 2; ++ch) {
        const size_t ga = (size_t)(q0 + wave * 16 + m) * rs + qcol + ch * 32 + quad * 8;
        const short8 q8 = *(const short8*)&base[ga];
        short8 qs;
#pragma unroll
        for (int j = 0; j < 8; ++j)
            qs[j] = (short)f2bf(bf2f((unsigned short)q8[j]) * 1.44269504088896f);
        Qf[ch] = qs;
    }

    f32x4 Oacc[4];
    const f32x4 zero = {0.f, 0.f, 0.f, 0.f};
#pragma unroll
    for (int nt = 0; nt < 4; ++nt) Oacc[nt] = zero;
    float lrow[4] = {0.f, 0.f, 0.f, 0.f};     // per-lane partial row sums

    // staging maps
    const int kr0 = tid >> 3,          kc0 = (tid & 7) * 8;          // rows 0..31
    const int kr1 = (tid + 256) >> 3,  kc1 = ((tid + 256) & 7) * 8;  // rows 32..63
    const int pk  = (tid >> 4) * 4;      // V patch: k-base (0,4,8,12)
    const int pd  = (tid & 15) * 4;      // V patch: d-base (0..60)
    // Vt swizzle: phys chunk = (k>>3) ^ ((d>>2)&7); uniform per thread-patch.
    const int vswz = ((pk >> 3) ^ ((pd >> 2) & 7)) * 8 + (pk & 7);

    // prefetch registers
    short8  pK0, pK1;
    ushort4 pV0, pV1, pV2, pV3;
    {   // load tile 0
        pK0 = *(const short8*)&base[(size_t)kr0 * rs + kcol + kc0];
        pK1 = *(const short8*)&base[(size_t)kr1 * rs + kcol + kc1];
        pV0 = *(const ushort4*)&base[(size_t)(pk + 0) * rs + vcol + pd];
        pV1 = *(const ushort4*)&base[(size_t)(pk + 1) * rs + vcol + pd];
        pV2 = *(const ushort4*)&base[(size_t)(pk + 2) * rs + vcol + pd];
        pV3 = *(const ushort4*)&base[(size_t)(pk + 3) * rs + vcol + pd];
    }

    for (int kt = 0; kt < ktEnd; ++kt) {
        const int kbase = kt * 64;
        __syncthreads();   // previous iter done reading Kh/Vt

        // ---- stage prefetched K/V to LDS (Vt chunk-swizzled) ----
        *(short8*)&Kh[kr0 * KS + kc0] = pK0;
        *(short8*)&Kh[kr1 * KS + kc1] = pK1;
        *(ushort4*)&Vt[(pd + 0) * KS + vswz] = make_ushort4(pV0.x, pV1.x, pV2.x, pV3.x);
        *(ushort4*)&Vt[(pd + 1) * KS + vswz] = make_ushort4(pV0.y, pV1.y, pV2.y, pV3.y);
        *(ushort4*)&Vt[(pd + 2) * KS + vswz] = make_ushort4(pV0.z, pV1.z, pV2.z, pV3.z);
        *(ushort4*)&Vt[(pd + 3) * KS + vswz] = make_ushort4(pV0.w, pV1.w, pV2.w, pV3.w);
        __syncthreads();

        // ---- issue loads for tile kt+1 (hidden behind compute below) ----
        if (kt + 1 < ktEnd) {
            const int nb = kbase + 64;
            pK0 = *(const short8*)&base[(size_t)(nb + kr0) * rs + kcol + kc0];
            pK1 = *(const short8*)&base[(size_t)(nb + kr1) * rs + kcol + kc1];
            pV0 = *(const ushort4*)&base[(size_t)(nb + pk + 0) * rs + vcol + pd];
            pV1 = *(const ushort4*)&base[(size_t)(nb + pk + 1) * rs + vcol + pd];
            pV2 = *(const ushort4*)&base[(size_t)(nb + pk + 2) * rs + vcol + pd];
            pV3 = *(const ushort4*)&base[(size_t)(nb + pk + 3) * rs + vcol + pd];
        }

        // ---- S' = (Q*log2e) · K^T ----
        f32x4 S4[4];
#pragma unroll
        for (int nt = 0; nt < 4; ++nt) S4[nt] = zero;
#pragma unroll
        for (int ch = 0; ch < 2; ++ch)
#pragma unroll
            for (int nt = 0; nt < 4; ++nt) {
                const short8 k8 = *(const short8*)&Kh[(nt * 16 + m) * KS + ch * 32 + quad * 8];
                S4[nt] = __builtin_amdgcn_mfma_f32_16x16x32_bf16(Qf[ch], k8, S4[nt], 0, 0, 0);
            }

        // ---- mask invalid keys (exp2(-1e30) underflows to exact 0) ----
        if (kbase + 64 > len) {
#pragma unroll
            for (int nt = 0; nt < 4; ++nt)
                if (kbase + nt * 16 + m >= len) {
#pragma unroll
                    for (int r = 0; r < 4; ++r) S4[nt][r] = -1e30f;
                }
        }

        // ---- p = exp2(S'); accumulate partial l; store P (bf16) ----
#pragma unroll
        for (int nt = 0; nt < 4; ++nt)
#pragma unroll
            for (int r = 0; r < 4; ++r) {
                const float p = __builtin_amdgcn_exp2f(S4[nt][r]);
                lrow[r] += p;
                PfU[(wave * 16 + quad * 4 + r) * PS2 + nt * 16 + m] = f2bf(p);
            }

        // ---- O += P · V (Vt read un-swizzled per (nt,ch,quad,m)) ----
#pragma unroll
        for (int ch = 0; ch < 2; ++ch) {
            const short8 P8 = *(const short8*)&PfU[(wave * 16 + m) * PS2 + ch * 32 + quad * 8];
#pragma unroll
            for (int nt = 0; nt < 4; ++nt) {
                const int pchunk = ((ch * 4 + quad) ^ ((nt * 4 + (m >> 2)) & 7)) * 8;
                const short8 v8 = *(const short8*)&Vt[(nt * 16 + m) * KS + pchunk];
                Oacc[nt] = __builtin_amdgcn_mfma_f32_16x16x32_bf16(P8, v8, Oacc[nt], 0, 0, 0);
            }
        }
    }

    // ---- single end-of-loop row-sum reduction over the 16 m-lanes ----
#pragma unroll
    for (int r = 0; r < 4; ++r) {
#pragma unroll
        for (int sh = 8; sh >= 1; sh >>= 1)
            lrow[r] += __shfl_xor(lrow[r], sh);
    }

    // ---- epilogue: /l, zero invalid q rows, bf16 store ----
#pragma unroll
    for (int r = 0; r < 4; ++r) {
        const int qrow = q0 + wave * 16 + quad * 4 + r;
        const size_t ob = (size_t)(b * Tc + qrow) * Dc + hh * DHc + m;
        if (qrow < len) {
            const float inv = 1.0f / lrow[r];
#pragma unroll
            for (int nt = 0; nt < 4; ++nt)
                oh[ob + nt * 16] = f2bf(Oacc[nt][r] * inv);
        } else {
#pragma unroll
            for (int nt = 0; nt < 4; ++nt)
                oh[ob + nt * 16] = 0;
        }
    }
}

// ---------------------------------------------------------------------------
// LN1: (outh,outl) = split_bf16(LN(X + Y) * mask). X,Y fp32.
// ---------------------------------------------------------------------------
__global__ __launch_bounds__(256) void ln_split_kernel(
    const float* __restrict__ X, const float* __restrict__ Y,
    const float* __restrict__ g, const float* __restrict__ beta,
    const int* __restrict__ lengths,
    unsigned short* __restrict__ outh, unsigned short* __restrict__ outl)
{
    __shared__ float red[4];
    const int row = blockIdx.x;
    const int b = row / Tc, t = row % Tc;
    const int len = lengths[b];
    const size_t basei = (size_t)row * Dc;
    const int tid = threadIdx.x;

    if (t >= len) {
        for (int j = tid; j < Dc; j += 256) { outh[basei + j] = 0; outl[basei + j] = 0; }
        return;
    }

    float v[3];
    float s = 0.f;
#pragma unroll
    for (int j = 0; j < 3; ++j) {
        int idx = tid + j * 256;
        v[j] = X[basei + idx] + Y[basei + idx];
        s += v[j];
    }
    const int lane = tid % 64, wid = tid / 64;
#pragma unroll
    for (int sh = 32; sh >= 1; sh >>= 1) s += __shfl_xor(s, sh);
    if (lane == 0) red[wid] = s;
    __syncthreads();
    s = red[0] + red[1] + red[2] + red[3];
    const float mu = s * (1.0f / Dc);

    float vs = 0.f;
#pragma unroll
    for (int j = 0; j < 3; ++j) { float dv = v[j] - mu; vs += dv * dv; }
    __syncthreads();
#pragma unroll
    for (int sh = 32; sh >= 1; sh >>= 1) vs += __shfl_xor(vs, sh);
    if (lane == 0) red[wid] = vs;
    __syncthreads();
    vs = red[0] + red[1] + red[2] + red[3];
    const float rstd = rsqrtf(vs * (1.0f / Dc) + 1e-5f);

#pragma unroll
    for (int j = 0; j < 3; ++j) {
        int idx = tid + j * 256;
        const float ov = (v[j] - mu) * rstd * g[idx] + beta[idx];
        unsigned short hh, ll;
        bsplit(ov, hh, ll);
        outh[basei + idx] = hh;
        outl[basei + idx] = ll;
    }
}

// ---------------------------------------------------------------------------
// LN2: out = LN((Xh+Xl) + Y) * mask, fp32 out. Y and out may alias (in-place).
// ---------------------------------------------------------------------------
__global__ __launch_bounds__(256) void ln2_kernel(
    const unsigned short* __restrict__ Xh, const unsigned short* __restrict__ Xl,
    const float* Y,
    const float* __restrict__ g, const float* __restrict__ beta,
    const int* __restrict__ lengths, float* out)
{
    __shared__ float red[4];
    const int row = blockIdx.x;
    const int b = row / Tc, t = row % Tc;
    const int len = lengths[b];
    const size_t basei = (size_t)row * Dc;
    const int tid = threadIdx.x;

    if (t >= len) {
        for (int j = tid; j < Dc; j += 256) out[basei + j] = 0.f;
        return;
    }

    float v[3];
    float s = 0.f;
#pragma unroll
    for (int j = 0; j < 3; ++j) {
        int idx = tid + j * 256;
        v[j] = bf2f(Xh[basei + idx]) + bf2f(Xl[basei + idx]) + Y[basei + idx];
        s += v[j];
    }
    const int lane = tid % 64, wid = tid / 64;
#pragma unroll
    for (int sh = 32; sh >= 1; sh >>= 1) s += __shfl_xor(s, sh);
    if (lane == 0) red[wid] = s;
    __syncthreads();
    s = red[0] + red[1] + red[2] + red[3];
    const float mu = s * (1.0f / Dc);

    float vs = 0.f;
#pragma unroll
    for (int j = 0; j < 3; ++j) { float dv = v[j] - mu; vs += dv * dv; }
    __syncthreads();
#pragma unroll
    for (int sh = 32; sh >= 1; sh >>= 1) vs += __shfl_xor(vs, sh);
    if (lane == 0) red[wid] = vs;
    __syncthreads();
    vs = red[0] + red[1] + red[2] + red[3];
    const float rstd = rsqrtf(vs * (1.0f / Dc) + 1e-5f);

#pragma unroll
    for (int j = 0; j < 3; ++j) {
        int idx = tid + j * 256;
        out[basei + idx] = (v[j] - mu) * rstd * g[idx] + beta[idx];
    }
}

// ---------------------------------------------------------------------------
// Workspace plan (bytes; peak 51,904,512 — R0 layout):
//   [0, 18.87M)        : qkvh -> projo fp32 [0,12.58M) -> fH head
//   [18.87M, 25.17M)   : xh -> ah -> fH tail  (fH = [0,25.17M) [4096,3072])
//   [25.17M, 31.46M)   : nh | [31.46M, 37.75M) : nl
//   [37.75M, 41.29M)   : wqkvT | [41.29M, 42.47M) : wprojT
//   [42.47M, 47.19M)   : wfcT  | [47.19M, 51.91M) : woutT
// ---------------------------------------------------------------------------
extern "C" void kernel_launch(void* const* d_in, const int* in_sizes, int n_in,
                              void* d_out, int out_size, void* d_ws, size_t ws_size,
                              hipStream_t stream)
{
    const float* x      = (const float*)d_in[0];
    const int*   lens   = (const int*)  d_in[1];
    const float* w_qkv  = (const float*)d_in[2];
    const float* b_qkv  = (const float*)d_in[3];
    const float* w_proj = (const float*)d_in[4];
    const float* b_proj = (const float*)d_in[5];
    const float* ln1_g  = (const float*)d_in[6];
    const float* ln1_b  = (const float*)d_in[7];
    const float* w_fc   = (const float*)d_in[8];
    const float* b_fc   = (const float*)d_in[9];
    const float* w_out  = (const float*)d_in[10];
    const float* b_out  = (const float*)d_in[11];
    const float* ln2_g  = (const float*)d_in[12];
    const float* ln2_b  = (const float*)d_in[13];

    if (ws_size < 51904512) return;  // -> validation mismatch, not a crash

    char* ws = (char*)d_ws;
    unsigned short* qkvh  = (unsigned short*)(ws + 0);           // [4096,2304]
    unsigned short* xh    = (unsigned short*)(ws + 18874368);    // [4096,768]
    unsigned short* ah    = xh;                                  // attn out (xh dead)
    float*          projo = (float*)(ws + 0);                    // [4096,768] fp32
    unsigned short* fH    = (unsigned short*)(ws + 0);           // [4096,3072]
    unsigned short* nh    = (unsigned short*)(ws + 25165824);    // [4096,768]
    unsigned short* nl    = (unsigned short*)(ws + 31457280);
    unsigned short* wqkvT = (unsigned short*)(ws + 37748736);
    unsigned short* wprojT= (unsigned short*)(ws + 41287680);
    unsigned short* wfcT  = (unsigned short*)(ws + 42467328);
    unsigned short* woutT = (unsigned short*)(ws + 47185920);
    float*          mbuf  = (float*)d_out;

    const dim3 blk(256);

    // 0) fused prepare: x cast + all weight transposes
    prepare_kernel<<<dim3(6528), blk, 0, stream>>>(
        x, w_qkv, w_proj, w_fc, w_out, xh, wqkvT, wprojT, wfcT, woutT);

    // 1) qkv = x @ w_qkv + b_qkv -> bf16  (TM=64/TN=128: 1152 blocks)
    gemm_bf16<64, 128, 3><<<dim3(D3 / 128, M_ROWS / 64), blk, 0, stream>>>(
        xh, wqkvT, b_qkv, nullptr, qkvh, M_ROWS, D3, Dc);

    // 2) attention v4 -> ah (bf16)  (768 blocks)
    flash_attn_bf16<<<dim3(Bc * Hc * (Tc / 64)), blk, 0, stream>>>(qkvh, lens, ah);

    // 3) proj: projo = a @ w_proj + b_proj (fp32)  (TN=64: 768 blocks)
    gemm_bf16<64, 64, 0><<<dim3(Dc / 64, M_ROWS / 64), blk, 0, stream>>>(
        ah, wprojT, b_proj, projo, nullptr, M_ROWS, Dc, Dc);

    // 4) n = LN(x + projo) * mask -> (nh, nl)
    ln_split_kernel<<<dim3(M_ROWS), blk, 0, stream>>>(x, projo, ln1_g, ln1_b, lens, nh, nl);

    // 5) fc: fH = bf16(gelu(n @ w_fc + b_fc))  (TM=64/TN=128: 1536 blocks)
    gemm_bf16<64, 128, 1><<<dim3(D4 / 128, M_ROWS / 64), blk, 0, stream>>>(
        nh, wfcT, b_fc, nullptr, fH, M_ROWS, D4, Dc);

    // 6) m = fH @ w_out + b_out -> d_out (fp32), K=3072  (TN=64: 768 blocks)
    gemm_bf16<64, 64, 0><<<dim3(Dc / 64, M_ROWS / 64), blk, 0, stream>>>(
        fH, woutT, b_out, mbuf, nullptr, M_ROWS, Dc, D4);

    // 7) h = LN((nh+nl) + m) * mask -> d_out (in-place)
    ln2_kernel<<<dim3(M_ROWS), blk, 0, stream>>>(nh, nl, mbuf, ln2_g, ln2_b, lens,
                                                 (float*)d_out);
}

// Round 8
// 300.122 us; speedup vs baseline: 1.2881x; 1.0490x over previous
//
#include <hip/hip_runtime.h>
#include <hip/hip_bf16.h>
#include <math.h>

// Problem constants
constexpr int Bc  = 2;
constexpr int Tc  = 2048;
constexpr int Dc  = 768;
constexpr int Hc  = 12;
constexpr int DHc = 64;
constexpr int M_ROWS = Bc * Tc;        // 4096
constexpr int D3  = 3 * Dc;            // 2304
constexpr int D4  = 4 * Dc;            // 3072

typedef __attribute__((ext_vector_type(8))) short short8;   // 8 bf16 (4 VGPRs)
typedef __attribute__((ext_vector_type(4))) float f32x4;    // MFMA acc

__device__ __forceinline__ unsigned short f2bf(float v) {
    union { __hip_bfloat16 b; unsigned short u; } cv;
    cv.b = __float2bfloat16(v);
    return cv.u;
}
__device__ __forceinline__ float bf2f(unsigned short u) {
    union { __hip_bfloat16 b; unsigned short u; } cv;
    cv.u = u;
    return __bfloat162float(cv.b);
}
__device__ __forceinline__ void bsplit(float v, unsigned short& h, unsigned short& l) {
    h = f2bf(v);
    l = f2bf(v - bf2f(h));
}

__device__ __forceinline__ float gelu_f(float x) {
    const float c = 0.79788456080286535588f; // sqrt(2/pi)
    return 0.5f * x * (1.0f + tanhf(c * (x + 0.044715f * x * x * x)));
}

// Async global->LDS, 16B per lane (LDS dest = wave-uniform base + lane*16).
__device__ __forceinline__ void glds16(const unsigned short* g, unsigned short* l) {
    __builtin_amdgcn_global_load_lds(
        (const __attribute__((address_space(1))) void*)g,
        (__attribute__((address_space(3))) void*)l, 16, 0, 0);
}

// ---------------------------------------------------------------------------
// Fused prepare: x cast + all 4 weight transpose-casts in ONE dispatch.
// ---------------------------------------------------------------------------
__device__ __forceinline__ void tcast8(
    const float* __restrict__ w, int ldw,
    unsigned short* __restrict__ th, int K, int N, int idx)
{
    const int n  = idx % N;
    const int k0 = (idx / N) * 8;
    unsigned short hv[8];
#pragma unroll
    for (int j = 0; j < 8; ++j)
        hv[j] = f2bf(w[(size_t)(k0 + j) * ldw + n]);
    const size_t o = (size_t)n * K + k0;
    *(ushort4*)(th + o)     = make_ushort4(hv[0], hv[1], hv[2], hv[3]);
    *(ushort4*)(th + o + 4) = make_ushort4(hv[4], hv[5], hv[6], hv[7]);
}

__global__ __launch_bounds__(256) void prepare_kernel(
    const float* __restrict__ x,
    const float* __restrict__ w_qkv, const float* __restrict__ w_proj,
    const float* __restrict__ w_fc,  const float* __restrict__ w_out,
    unsigned short* __restrict__ xh,
    unsigned short* __restrict__ wqkvT, unsigned short* __restrict__ wprojT,
    unsigned short* __restrict__ wfcT,  unsigned short* __restrict__ woutT)
{
    int id = blockIdx.x * 256 + threadIdx.x;
    if (id < 786432) {
        const float4 v = *(const float4*)(x + (size_t)id * 4);
        *(ushort4*)(xh + (size_t)id * 4) =
            make_ushort4(f2bf(v.x), f2bf(v.y), f2bf(v.z), f2bf(v.w));
        return;
    }
    id -= 786432;
    if (id < 221184) { tcast8(w_qkv, D3, wqkvT, Dc, D3, id); return; }
    id -= 221184;
    if (id < 73728)  { tcast8(w_proj, Dc, wprojT, Dc, Dc, id); return; }
    id -= 73728;
    if (id < 294912) { tcast8(w_fc, D4, wfcT, Dc, D4, id); return; }
    id -= 294912;
    tcast8(w_out, Dc, woutT, D4, Dc, id);
}

// ---------------------------------------------------------------------------
// R0-proven bf16 MFMA GEMM, BK=64, single-buffered, TN-parameterized
// (unchanged from R7). Tile TM x TN, 256 thr = 4 waves.
// MODE: 0 = fp32 out (+bias) | 1 = gelu -> bf16 out (+bias) | 3 = bf16 out
// ---------------------------------------------------------------------------
template <int TM, int TN, int MODE>
__global__ __launch_bounds__(256) void gemm_bf16(
    const unsigned short* __restrict__ A,
    const unsigned short* __restrict__ B,
    const float* __restrict__ bias,
    float* __restrict__ C, unsigned short* __restrict__ Cb,
    int M, int N, int K)
{
    constexpr int MT = TM / 32;              // m-tiles per wave
    constexpr int NT = TN / 32;              // n-tiles per wave
    __shared__ unsigned short Ash[TM * 64];
    __shared__ unsigned short Bsh[TN * 64];

    const int tid  = threadIdx.x;
    const int n0   = blockIdx.x * TN;
    const int m0   = blockIdx.y * TM;
    const int wave = tid >> 6;
    const int lane = tid & 63;
    const int wm   = (wave >> 1) * (TM / 2);
    const int wn   = (wave & 1) * (TN / 2);
    const int lrow = lane & 15;
    const int quad = lane >> 4;
    const int swz  = lrow & 7;               // frag-read row swizzle key

    f32x4 acc[MT][NT];
    const f32x4 zero = {0.f, 0.f, 0.f, 0.f};
#pragma unroll
    for (int i = 0; i < MT; ++i)
#pragma unroll
        for (int j = 0; j < NT; ++j) acc[i][j] = zero;

    // staging: one glds16 issue covers 8 rows x 128 B. lane -> (row, chunk).
    const int l8r  = lane >> 3;              // 0..7 row within issue
    const int csel = ((lane & 7) ^ l8r) * 8; // swizzled global chunk (shorts)

    for (int ks = 0; ks < K; ks += 64) {
        __syncthreads();
#pragma unroll
        for (int j = 0; j < TM / 32; ++j) {
            const int rbase = wave * (TM / 4) + j * 8;
            const size_t g = (size_t)(m0 + rbase + l8r) * K + ks + csel;
            glds16(A + g, &Ash[rbase * 64]);
        }
#pragma unroll
        for (int j = 0; j < TN / 32; ++j) {
            const int rbase = wave * (TN / 4) + j * 8;
            const size_t g = (size_t)(n0 + rbase + l8r) * K + ks + csel;
            glds16(B + g, &Bsh[rbase * 64]);
        }
        __syncthreads();

#pragma unroll
        for (int kk = 0; kk < 2; ++kk) {
            short8 fa[MT], fb[NT];
            const int cl = kk * 4 + quad;    // logical chunk
            const int pc = (cl ^ swz) * 8;   // physical chunk offset (shorts)
#pragma unroll
            for (int t = 0; t < MT; ++t)
                fa[t] = *(const short8*)&Ash[(wm + t * 16 + lrow) * 64 + pc];
#pragma unroll
            for (int t = 0; t < NT; ++t)
                fb[t] = *(const short8*)&Bsh[(wn + t * 16 + lrow) * 64 + pc];
#pragma unroll
            for (int mt = 0; mt < MT; ++mt)
#pragma unroll
                for (int nt = 0; nt < NT; ++nt)
                    acc[mt][nt] = __builtin_amdgcn_mfma_f32_16x16x32_bf16(
                        fa[mt], fb[nt], acc[mt][nt], 0, 0, 0);
        }
    }

#pragma unroll
    for (int mt = 0; mt < MT; ++mt) {
        const int rowb = m0 + wm + mt * 16 + quad * 4;
#pragma unroll
        for (int nt = 0; nt < NT; ++nt) {
            const int col = n0 + wn + nt * 16 + lrow;
            const float bv = bias[col];
#pragma unroll
            for (int r = 0; r < 4; ++r) {
                const size_t ci = (size_t)(rowb + r) * N + col;
                if (MODE == 0) {
                    C[ci] = acc[mt][nt][r] + bv;
                } else if (MODE == 1) {
                    Cb[ci] = f2bf(gelu_f(acc[mt][nt][r] + bv));
                } else { // MODE 3
                    Cb[ci] = f2bf(acc[mt][nt][r] + bv);
                }
            }
        }
    }
}

// ---------------------------------------------------------------------------
// bf16 MFMA flash attention, v7 = v4 + PfU bank-conflict fix.
// Diagnosis (R7 counters): SQ_LDS_BANK_CONFLICT = 8.65M cycles/dispatch
// (~20% of kernel). Lane-level bank audit: Kh/Vt stores+reads and PfU b128
// reads are conflict-free; the P stores were the source — with PS2=72,
// 4 rows = 144 dwords == 16 (mod 32), so quads {0,2} and {1,3} collide ->
// 4 lanes/bank on 16 scalar stores per tile.
// Fix: PS2 = 68 -> 4 rows = 136 dwords == 8 (mod 32): store bank =
// 8*quad + 2r + m/2, all quads in distinct octets -> conflict-free.
// Rows are now only 8B-aligned, so P reads use 2x ushort4 (ds_read_b64)
// per fragment — audited at the 8B-op floor (4 lanes/even bank), no
// conflict. Everything else identical to v4.
// ---------------------------------------------------------------------------
constexpr int KS  = 72;  // K/V LDS row stride (shorts): 144B rows, 16B-aligned
constexpr int PS2 = 68;  // P LDS row stride (shorts): 136B rows, 8B-aligned

__global__ __launch_bounds__(256) void flash_attn_bf16(
    const unsigned short* __restrict__ qkv,
    const int* __restrict__ lengths,
    unsigned short* __restrict__ oh)
{
    __shared__ unsigned short Kh[64 * KS];
    __shared__ unsigned short Vt[64 * KS];    // V^T: [d][k], chunk-swizzled
    __shared__ unsigned short PfU[64 * PS2];  // P bf16, wave-private strips

    const int tid  = threadIdx.x;
    const int wave = tid >> 6;
    const int lane = tid & 63;
    const int m    = lane & 15;
    const int quad = lane >> 4;

    const int nqt = Tc / 64;                  // 32
    const int qt  = blockIdx.x % nqt;
    const int bh  = blockIdx.x / nqt;
    const int hh  = bh % Hc;
    const int b   = bh / Hc;
    const int len = lengths[b];
    const int q0  = qt * 64;
    const size_t rs = (size_t)D3;
    const unsigned short* base = qkv + (size_t)b * Tc * rs;
    const int qcol = hh * DHc;
    const int kcol = Dc + hh * DHc;
    const int vcol = 2 * Dc + hh * DHc;

    // ---- q-tile fully masked: write zeros, done ----
    if (q0 >= len) {
#pragma unroll
        for (int r = 0; r < 4; ++r) {
            const int qrow = q0 + wave * 16 + quad * 4 + r;
            const size_t ob = (size_t)(b * Tc + qrow) * Dc + hh * DHc + m;
#pragma unroll
            for (int nt = 0; nt < 4; ++nt) oh[ob + nt * 16] = 0;
        }
        return;
    }

    const int ktEnd = (min(len, Tc) + 63) >> 6;   // skip fully-masked K tiles

    // ---- preload Q fragments (A-layout), pre-scaled by log2(e) ----
    short8 Qf[2];
#pragma unroll
    for (int ch = 0; ch < 2; ++ch) {
        const size_t ga = (size_t)(q0 + wave * 16 + m) * rs + qcol + ch * 32 + quad * 8;
        const short8 q8 = *(const short8*)&base[ga];
        short8 qs;
#pragma unroll
        for (int j = 0; j < 8; ++j)
            qs[j] = (short)f2bf(bf2f((unsigned short)q8[j]) * 1.44269504088896f);
        Qf[ch] = qs;
    }

    f32x4 Oacc[4];
    const f32x4 zero = {0.f, 0.f, 0.f, 0.f};
#pragma unroll
    for (int nt = 0; nt < 4; ++nt) Oacc[nt] = zero;
    float lrow[4] = {0.f, 0.f, 0.f, 0.f};     // per-lane partial row sums

    // staging maps
    const int kr0 = tid >> 3,          kc0 = (tid & 7) * 8;          // rows 0..31
    const int kr1 = (tid + 256) >> 3,  kc1 = ((tid + 256) & 7) * 8;  // rows 32..63
    const int pk  = (tid >> 4) * 4;      // V patch: k-base (0,4,8,12)
    const int pd  = (tid & 15) * 4;      // V patch: d-base (0..60)
    // Vt swizzle: phys chunk = (k>>3) ^ ((d>>2)&7); uniform per thread-patch.
    const int vswz = ((pk >> 3) ^ ((pd >> 2) & 7)) * 8 + (pk & 7);

    // prefetch registers
    short8  pK0, pK1;
    ushort4 pV0, pV1, pV2, pV3;
    {   // load tile 0
        pK0 = *(const short8*)&base[(size_t)kr0 * rs + kcol + kc0];
        pK1 = *(const short8*)&base[(size_t)kr1 * rs + kcol + kc1];
        pV0 = *(const ushort4*)&base[(size_t)(pk + 0) * rs + vcol + pd];
        pV1 = *(const ushort4*)&base[(size_t)(pk + 1) * rs + vcol + pd];
        pV2 = *(const ushort4*)&base[(size_t)(pk + 2) * rs + vcol + pd];
        pV3 = *(const ushort4*)&base[(size_t)(pk + 3) * rs + vcol + pd];
    }

    for (int kt = 0; kt < ktEnd; ++kt) {
        const int kbase = kt * 64;
        __syncthreads();   // previous iter done reading Kh/Vt

        // ---- stage prefetched K/V to LDS (Vt chunk-swizzled) ----
        *(short8*)&Kh[kr0 * KS + kc0] = pK0;
        *(short8*)&Kh[kr1 * KS + kc1] = pK1;
        *(ushort4*)&Vt[(pd + 0) * KS + vswz] = make_ushort4(pV0.x, pV1.x, pV2.x, pV3.x);
        *(ushort4*)&Vt[(pd + 1) * KS + vswz] = make_ushort4(pV0.y, pV1.y, pV2.y, pV3.y);
        *(ushort4*)&Vt[(pd + 2) * KS + vswz] = make_ushort4(pV0.z, pV1.z, pV2.z, pV3.z);
        *(ushort4*)&Vt[(pd + 3) * KS + vswz] = make_ushort4(pV0.w, pV1.w, pV2.w, pV3.w);
        __syncthreads();

        // ---- issue loads for tile kt+1 (hidden behind compute below) ----
        if (kt + 1 < ktEnd) {
            const int nb = kbase + 64;
            pK0 = *(const short8*)&base[(size_t)(nb + kr0) * rs + kcol + kc0];
            pK1 = *(const short8*)&base[(size_t)(nb + kr1) * rs + kcol + kc1];
            pV0 = *(const ushort4*)&base[(size_t)(nb + pk + 0) * rs + vcol + pd];
            pV1 = *(const ushort4*)&base[(size_t)(nb + pk + 1) * rs + vcol + pd];
            pV2 = *(const ushort4*)&base[(size_t)(nb + pk + 2) * rs + vcol + pd];
            pV3 = *(const ushort4*)&base[(size_t)(nb + pk + 3) * rs + vcol + pd];
        }

        // ---- S' = (Q*log2e) · K^T ----
        f32x4 S4[4];
#pragma unroll
        for (int nt = 0; nt < 4; ++nt) S4[nt] = zero;
#pragma unroll
        for (int ch = 0; ch < 2; ++ch)
#pragma unroll
            for (int nt = 0; nt < 4; ++nt) {
                const short8 k8 = *(const short8*)&Kh[(nt * 16 + m) * KS + ch * 32 + quad * 8];
                S4[nt] = __builtin_amdgcn_mfma_f32_16x16x32_bf16(Qf[ch], k8, S4[nt], 0, 0, 0);
            }

        // ---- mask invalid keys (exp2(-1e30) underflows to exact 0) ----
        if (kbase + 64 > len) {
#pragma unroll
            for (int nt = 0; nt < 4; ++nt)
                if (kbase + nt * 16 + m >= len) {
#pragma unroll
                    for (int r = 0; r < 4; ++r) S4[nt][r] = -1e30f;
                }
        }

        // ---- p = exp2(S'); accumulate partial l; store P (bf16) ----
        // store bank = 8*quad + 2r + m/2 (PS2=68) -> conflict-free
#pragma unroll
        for (int nt = 0; nt < 4; ++nt)
#pragma unroll
            for (int r = 0; r < 4; ++r) {
                const float p = __builtin_amdgcn_exp2f(S4[nt][r]);
                lrow[r] += p;
                PfU[(wave * 16 + quad * 4 + r) * PS2 + nt * 16 + m] = f2bf(p);
            }

        // ---- O += P · V (P read as 2x ushort4: rows are 8B-aligned) ----
        const int pbase = (wave * 16 + m) * PS2;
#pragma unroll
        for (int ch = 0; ch < 2; ++ch) {
            union { ushort4 u4[2]; short8 s8; } pu;
            pu.u4[0] = *(const ushort4*)&PfU[pbase + ch * 32 + quad * 8];
            pu.u4[1] = *(const ushort4*)&PfU[pbase + ch * 32 + quad * 8 + 4];
            const short8 P8 = pu.s8;
#pragma unroll
            for (int nt = 0; nt < 4; ++nt) {
                const int pchunk = ((ch * 4 + quad) ^ ((nt * 4 + (m >> 2)) & 7)) * 8;
                const short8 v8 = *(const short8*)&Vt[(nt * 16 + m) * KS + pchunk];
                Oacc[nt] = __builtin_amdgcn_mfma_f32_16x16x32_bf16(P8, v8, Oacc[nt], 0, 0, 0);
            }
        }
    }

    // ---- single end-of-loop row-sum reduction over the 16 m-lanes ----
#pragma unroll
    for (int r = 0; r < 4; ++r) {
#pragma unroll
        for (int sh = 8; sh >= 1; sh >>= 1)
            lrow[r] += __shfl_xor(lrow[r], sh);
    }

    // ---- epilogue: /l, zero invalid q rows, bf16 store ----
#pragma unroll
    for (int r = 0; r < 4; ++r) {
        const int qrow = q0 + wave * 16 + quad * 4 + r;
        const size_t ob = (size_t)(b * Tc + qrow) * Dc + hh * DHc + m;
        if (qrow < len) {
            const float inv = 1.0f / lrow[r];
#pragma unroll
            for (int nt = 0; nt < 4; ++nt)
                oh[ob + nt * 16] = f2bf(Oacc[nt][r] * inv);
        } else {
#pragma unroll
            for (int nt = 0; nt < 4; ++nt)
                oh[ob + nt * 16] = 0;
        }
    }
}

// ---------------------------------------------------------------------------
// LN1: (outh,outl) = split_bf16(LN(X + Y) * mask). X,Y fp32.
// Single-pass: one reduction of (sum, sumsq), var = E[v^2]-mu^2 (safe here:
// mu ~ 0.03, var ~ 1 -> no cancellation). 1 barrier instead of 3.
// ---------------------------------------------------------------------------
__global__ __launch_bounds__(256) void ln_split_kernel(
    const float* __restrict__ X, const float* __restrict__ Y,
    const float* __restrict__ g, const float* __restrict__ beta,
    const int* __restrict__ lengths,
    unsigned short* __restrict__ outh, unsigned short* __restrict__ outl)
{
    __shared__ float red[8];
    const int row = blockIdx.x;
    const int b = row / Tc, t = row % Tc;
    const int len = lengths[b];
    const size_t basei = (size_t)row * Dc;
    const int tid = threadIdx.x;

    if (t >= len) {
        for (int j = tid; j < Dc; j += 256) { outh[basei + j] = 0; outl[basei + j] = 0; }
        return;
    }

    float v[3];
    float s = 0.f, s2 = 0.f;
#pragma unroll
    for (int j = 0; j < 3; ++j) {
        int idx = tid + j * 256;
        v[j] = X[basei + idx] + Y[basei + idx];
        s  += v[j];
        s2 += v[j] * v[j];
    }
    const int lane = tid % 64, wid = tid / 64;
#pragma unroll
    for (int sh = 32; sh >= 1; sh >>= 1) {
        s  += __shfl_xor(s, sh);
        s2 += __shfl_xor(s2, sh);
    }
    if (lane == 0) { red[wid] = s; red[4 + wid] = s2; }
    __syncthreads();
    s  = red[0] + red[1] + red[2] + red[3];
    s2 = red[4] + red[5] + red[6] + red[7];
    const float mu   = s * (1.0f / Dc);
    const float var  = s2 * (1.0f / Dc) - mu * mu;
    const float rstd = rsqrtf(var + 1e-5f);

#pragma unroll
    for (int j = 0; j < 3; ++j) {
        int idx = tid + j * 256;
        const float ov = (v[j] - mu) * rstd * g[idx] + beta[idx];
        unsigned short hh, ll;
        bsplit(ov, hh, ll);
        outh[basei + idx] = hh;
        outl[basei + idx] = ll;
    }
}

// ---------------------------------------------------------------------------
// LN2: out = LN((Xh+Xl) + Y) * mask, fp32 out. Y and out may alias (in-place).
// Single-pass sum/sumsq as in LN1.
// ---------------------------------------------------------------------------
__global__ __launch_bounds__(256) void ln2_kernel(
    const unsigned short* __restrict__ Xh, const unsigned short* __restrict__ Xl,
    const float* Y,
    const float* __restrict__ g, const float* __restrict__ beta,
    const int* __restrict__ lengths, float* out)
{
    __shared__ float red[8];
    const int row = blockIdx.x;
    const int b = row / Tc, t = row % Tc;
    const int len = lengths[b];
    const size_t basei = (size_t)row * Dc;
    const int tid = threadIdx.x;

    if (t >= len) {
        for (int j = tid; j < Dc; j += 256) out[basei + j] = 0.f;
        return;
    }

    float v[3];
    float s = 0.f, s2 = 0.f;
#pragma unroll
    for (int j = 0; j < 3; ++j) {
        int idx = tid + j * 256;
        v[j] = bf2f(Xh[basei + idx]) + bf2f(Xl[basei + idx]) + Y[basei + idx];
        s  += v[j];
        s2 += v[j] * v[j];
    }
    const int lane = tid % 64, wid = tid / 64;
#pragma unroll
    for (int sh = 32; sh >= 1; sh >>= 1) {
        s  += __shfl_xor(s, sh);
        s2 += __shfl_xor(s2, sh);
    }
    if (lane == 0) { red[wid] = s; red[4 + wid] = s2; }
    __syncthreads();
    s  = red[0] + red[1] + red[2] + red[3];
    s2 = red[4] + red[5] + red[6] + red[7];
    const float mu   = s * (1.0f / Dc);
    const float var  = s2 * (1.0f / Dc) - mu * mu;
    const float rstd = rsqrtf(var + 1e-5f);

#pragma unroll
    for (int j = 0; j < 3; ++j) {
        int idx = tid + j * 256;
        out[basei + idx] = (v[j] - mu) * rstd * g[idx] + beta[idx];
    }
}

// ---------------------------------------------------------------------------
// Workspace plan (bytes; peak 51,904,512 — R0 layout):
//   [0, 18.87M)        : qkvh -> projo fp32 [0,12.58M) -> fH head
//   [18.87M, 25.17M)   : xh -> ah -> fH tail  (fH = [0,25.17M) [4096,3072])
//   [25.17M, 31.46M)   : nh | [31.46M, 37.75M) : nl
//   [37.75M, 41.29M)   : wqkvT | [41.29M, 42.47M) : wprojT
//   [42.47M, 47.19M)   : wfcT  | [47.19M, 51.91M) : woutT
// ---------------------------------------------------------------------------
extern "C" void kernel_launch(void* const* d_in, const int* in_sizes, int n_in,
                              void* d_out, int out_size, void* d_ws, size_t ws_size,
                              hipStream_t stream)
{
    const float* x      = (const float*)d_in[0];
    const int*   lens   = (const int*)  d_in[1];
    const float* w_qkv  = (const float*)d_in[2];
    const float* b_qkv  = (const float*)d_in[3];
    const float* w_proj = (const float*)d_in[4];
    const float* b_proj = (const float*)d_in[5];
    const float* ln1_g  = (const float*)d_in[6];
    const float* ln1_b  = (const float*)d_in[7];
    const float* w_fc   = (const float*)d_in[8];
    const float* b_fc   = (const float*)d_in[9];
    const float* w_out  = (const float*)d_in[10];
    const float* b_out  = (const float*)d_in[11];
    const float* ln2_g  = (const float*)d_in[12];
    const float* ln2_b  = (const float*)d_in[13];

    if (ws_size < 51904512) return;  // -> validation mismatch, not a crash

    char* ws = (char*)d_ws;
    unsigned short* qkvh  = (unsigned short*)(ws + 0);           // [4096,2304]
    unsigned short* xh    = (unsigned short*)(ws + 18874368);    // [4096,768]
    unsigned short* ah    = xh;                                  // attn out (xh dead)
    float*          projo = (float*)(ws + 0);                    // [4096,768] fp32
    unsigned short* fH    = (unsigned short*)(ws + 0);           // [4096,3072]
    unsigned short* nh    = (unsigned short*)(ws + 25165824);    // [4096,768]
    unsigned short* nl    = (unsigned short*)(ws + 31457280);
    unsigned short* wqkvT = (unsigned short*)(ws + 37748736);
    unsigned short* wprojT= (unsigned short*)(ws + 41287680);
    unsigned short* wfcT  = (unsigned short*)(ws + 42467328);
    unsigned short* woutT = (unsigned short*)(ws + 47185920);
    float*          mbuf  = (float*)d_out;

    const dim3 blk(256);

    // 0) fused prepare: x cast + all weight transposes
    prepare_kernel<<<dim3(6528), blk, 0, stream>>>(
        x, w_qkv, w_proj, w_fc, w_out, xh, wqkvT, wprojT, wfcT, woutT);

    // 1) qkv = x @ w_qkv + b_qkv -> bf16  (TM=64/TN=128: 1152 blocks)
    gemm_bf16<64, 128, 3><<<dim3(D3 / 128, M_ROWS / 64), blk, 0, stream>>>(
        xh, wqkvT, b_qkv, nullptr, qkvh, M_ROWS, D3, Dc);

    // 2) attention v7 -> ah (bf16)  (768 blocks)
    flash_attn_bf16<<<dim3(Bc * Hc * (Tc / 64)), blk, 0, stream>>>(qkvh, lens, ah);

    // 3) proj: projo = a @ w_proj + b_proj (fp32)  (TN=64: 768 blocks)
    gemm_bf16<64, 64, 0><<<dim3(Dc / 64, M_ROWS / 64), blk, 0, stream>>>(
        ah, wprojT, b_proj, projo, nullptr, M_ROWS, Dc, Dc);

    // 4) n = LN(x + projo) * mask -> (nh, nl)
    ln_split_kernel<<<dim3(M_ROWS), blk, 0, stream>>>(x, projo, ln1_g, ln1_b, lens, nh, nl);

    // 5) fc: fH = bf16(gelu(n @ w_fc + b_fc))  (TM=64/TN=128: 1536 blocks)
    gemm_bf16<64, 128, 1><<<dim3(D4 / 128, M_ROWS / 64), blk, 0, stream>>>(
        nh, wfcT, b_fc, nullptr, fH, M_ROWS, D4, Dc);

    // 6) m = fH @ w_out + b_out -> d_out (fp32), K=3072  (TN=64: 768 blocks)
    gemm_bf16<64, 64, 0><<<dim3(Dc / 64, M_ROWS / 64), blk, 0, stream>>>(
        fH, woutT, b_out, mbuf, nullptr, M_ROWS, Dc, D4);

    // 7) h = LN((nh+nl) + m) * mask -> d_out (in-place)
    ln2_kernel<<<dim3(M_ROWS), blk, 0, stream>>>(nh, nl, mbuf, ln2_g, ln2_b, lens,
                                                 (float*)d_out);
}